// Round 4
// baseline (252.624 us; speedup 1.0000x reference)
//
#include <hip/hip_runtime.h>
#include <stdint.h>

#define D   64
#define L   50
#define NUM_U 30000
#define NUM_I 20000
#define MROWS 50
#define PW3 (MROWS * 32 + 96 + 192)   // mailbox 1600 dw | dla 96 | escf 192 = 1888 dw
#define GEMM_BLKS 782                 // 3125 row-tiles of 16, 4 waves/block

// r9: 241.5us (attn 144, VALU42/occ53). r10: global gathers REGRESSED (186).
// r11: DMA mailbox fill + chunk-XOR swizzle: attn 137.7. Sums u16 gathers
//      8-way-ish bank conflict (7.7M): XOR key k&7 uniform per instruction.
// r12: prep -> MFMA. Total 227 but residue ~90us is HARNESS overhead (16
//      reset dispatches/iter), NOT prep (old prep ~6us). Lever = attn only.
// r13: (1) swizzle extended to (row&7)^(((row>>3)&3)<<1): q4 enters the bank
//      index -> sums gather provably conflict-free (1 addr/bank/instr);
//      (2) dh/lm A-frags direct from global regs (kill dla RAW chain);
//      (3) tek B-frags prefetched pre-rank (hide VMEM under rank+softmax).

typedef __attribute__((ext_vector_type(8))) short short8x;   // 8 bf16
typedef __attribute__((ext_vector_type(4))) float f32x4;     // MFMA acc

__device__ __forceinline__ float lof(unsigned int u) {
    union { unsigned int i; float f; } v; v.i = u << 16; return v.f;
}
__device__ __forceinline__ float hif(unsigned int u) {
    union { unsigned int i; float f; } v; v.i = u & 0xffff0000u; return v.f;
}
__device__ __forceinline__ unsigned int f2bfbits(float f) {
    union { float f; unsigned int i; } v; v.f = f;
    return (v.i + 0x7fffu + ((v.i >> 16) & 1u)) >> 16;   // RNE
}
__device__ __forceinline__ unsigned int packbf(float a, float b) {
    return f2bfbits(a) | (f2bfbits(b) << 16);
}
__device__ __forceinline__ float rl(float v, int l) {
    return __int_as_float(__builtin_amdgcn_readlane(__float_as_int(v), l));
}
__device__ __forceinline__ int rli(int v, int l) {
    return __builtin_amdgcn_readlane(v, l);
}
__device__ __forceinline__ void gload_lds16(const void* g, void* l) {
    __builtin_amdgcn_global_load_lds(
        (const __attribute__((address_space(1))) unsigned int*)g,
        (__attribute__((address_space(3))) unsigned int*)l, 16, 0, 0);
}

// ---------------- K1: fused prep: H = feat@W (MFMA) + bf16 weight packing ---
__global__ __launch_bounds__(256) void prep(
    const float* __restrict__ user_feat, const float* __restrict__ item_feat,
    const float* __restrict__ W_u, const float* __restrict__ W_i,
    const float* __restrict__ Wg_i, const float* __restrict__ Wg_u,
    const float* __restrict__ te_i, const float* __restrict__ te_u,
    const float* __restrict__ tk_i, const float* __restrict__ tk_u,
    unsigned int* __restrict__ H,
    unsigned short* __restrict__ WgPi, unsigned short* __restrict__ WgPu,
    unsigned short* __restrict__ tePi, unsigned short* __restrict__ tePu,
    unsigned short* __restrict__ tkPi, unsigned short* __restrict__ tkPu)
{
    const int tid = threadIdx.x;
    if (blockIdx.x < GEMM_BLKS) {
        const int lane = tid & 63, wid = tid >> 6;
        const int tile = blockIdx.x * 4 + wid;            // 16 rows per tile
        if (tile >= 3125) return;                         // 3125*16 = 50000 exact
        const int r0 = tile * 16;
        const float* src; const float* W;
        if (r0 < NUM_U) { src = user_feat + (size_t)r0 * D;            W = W_u; }
        else            { src = item_feat + (size_t)(r0 - NUM_U) * D;  W = W_i; }
        const int q4 = lane >> 4, c16 = lane & 15;

        // B-frags: feat rows. B[n=c16][k=kt*32+q4*8+j], coalesced float4 pairs.
        short8x bf[2];
#pragma unroll
        for (int kt = 0; kt < 2; kt++) {
            const float* fp = src + c16 * D + kt * 32 + q4 * 8;
            float4 x = *(const float4*)fp;
            float4 y = *(const float4*)(fp + 4);
            union { short8x v; unsigned int u[4]; } t2;
            t2.u[0] = packbf(x.x, x.y); t2.u[1] = packbf(x.z, x.w);
            t2.u[2] = packbf(y.x, y.y); t2.u[3] = packbf(y.z, y.w);
            bf[kt] = t2.v;
        }
        // A-frags: W^T. A[m=c16+16mt][k] = W[k][c16+16mt]; W is 16KB, L1-hot.
        f32x4 zero4 = {0.f, 0.f, 0.f, 0.f};
        f32x4 acc[4];
#pragma unroll
        for (int mt = 0; mt < 4; mt++) acc[mt] = zero4;
#pragma unroll
        for (int kt = 0; kt < 2; kt++) {
#pragma unroll
            for (int mt = 0; mt < 4; mt++) {
                union { short8x v; unsigned short u[8]; } a;
#pragma unroll
                for (int j = 0; j < 8; j++)
                    a.u[j] = (unsigned short)f2bfbits(
                        W[(kt * 32 + q4 * 8 + j) * D + c16 + 16 * mt]);
                acc[mt] = __builtin_amdgcn_mfma_f32_16x16x32_bf16(a.v, bf[kt], acc[mt], 0, 0, 0);
            }
        }
        // D[m][n]: col(c16) = feat row n, reg row = m = q4*4+r -> H col.
        unsigned int* Hrow = H + (size_t)(r0 + c16) * 32;
#pragma unroll
        for (int mt = 0; mt < 4; mt++) {
            uint2 pk;
            pk.x = packbf(acc[mt][0], acc[mt][1]);
            pk.y = packbf(acc[mt][2], acc[mt][3]);
            *(uint2*)(Hrow + 8 * mt + 2 * q4) = pk;
        }
    } else {
        int gid = (blockIdx.x - GEMM_BLKS) * 256 + tid;   // 16 blocks, gs=4096
        for (int idx = gid; idx < 8192; idx += 4096) {
            int n = idx >> 7, k = idx & 127;
            WgPi[idx] = (unsigned short)f2bfbits(Wg_i[k * 64 + n]);
            WgPu[idx] = (unsigned short)f2bfbits(Wg_u[k * 64 + n]);
        }
        {
            int idx = gid;                                // 4096 elements, 1 iter
            int r = idx >> 6, k = idx & 63;
            tePi[idx] = (r < L) ? (unsigned short)f2bfbits(te_i[r * 64 + k]) : 0;
            tePu[idx] = (r < L) ? (unsigned short)f2bfbits(te_u[r * 64 + k]) : 0;
            int d = idx >> 6, rr = idx & 63;
            tkPi[idx] = (rr < L) ? (unsigned short)f2bfbits(tk_i[rr * 64 + d]) : 0;
            tkPu[idx] = (rr < L) ? (unsigned short)f2bfbits(tk_u[rr * 64 + d]) : 0;
        }
    }
}

// ---------------- K2: fused attention, both sides, MFMA math ----------------
// Swizzle: LDS[row][pc] = G[row][pc ^ swz(row)], swz(row) = (row&7) ^
// (((row>>3)&3)<<1). Sums gather: per instruction each of 32 banks sees
// exactly one address (conflict-free); scores b128 stays <=2-way per phase.
__global__ __launch_bounds__(256, 5) void attn_fused(
    const unsigned int* __restrict__ H,
    const float* __restrict__ user_feat, const float* __restrict__ item_feat,
    const unsigned short* __restrict__ WgPi, const unsigned short* __restrict__ WgPu,
    const unsigned short* __restrict__ tePi, const unsigned short* __restrict__ tePu,
    const unsigned short* __restrict__ tkPi, const unsigned short* __restrict__ tkPu,
    const int* __restrict__ item_nbr, const int* __restrict__ item_time,
    const int* __restrict__ user_nbr, const int* __restrict__ user_time,
    float* __restrict__ out)
{
    __shared__ unsigned int lds[4 * PW3];   // 30208 B -> 5 blocks/CU

    const int tid = threadIdx.x, lane = tid & 63, wid = tid >> 6;
    const bool iside = blockIdx.x < (NUM_I / 4);
    const int bb = iside ? blockIdx.x : blockIdx.x - NUM_I / 4;
    const int n = bb * 4 + wid;
    const int src_base = iside ? 0 : NUM_U;
    const int dst_base = iside ? NUM_U : 0;
    const float* dst_feat = iside ? item_feat : user_feat;
    const unsigned short* WgP  = iside ? WgPi : WgPu;
    const unsigned short* teP  = iside ? tePi : tePu;
    const unsigned short* tekP = iside ? tkPi : tkPu;
    const int* nbr   = iside ? item_nbr  : user_nbr;
    const int* timev = iside ? item_time : user_time;
    float* outp = out + (iside ? (size_t)NUM_U * D : 0);

    const int q4 = lane >> 4, c16 = lane & 15;

    const unsigned int*   Hsrc = H + (size_t)src_base * 32;
    const unsigned short* Hs16 = (const unsigned short*)H + (size_t)src_base * 64;
    const unsigned short* Hd16 = (const unsigned short*)H + (size_t)dst_base * 64;

    // per-wave LDS slices
    unsigned int*   wld  = lds + wid * PW3;
    unsigned int*   mbw  = wld;                               // 50 rows x 32 dw, swizzled
    unsigned short* dla  = (unsigned short*)(wld + MROWS * 32);   // alpha|a1|beta
    float*          escf = (float*)(wld + MROWS * 32 + 96);       // e|e1|teh (192 f32)
    unsigned short* cat  = (unsigned short*)(wld + MROWS * 32 + 96); // overlay [hl|hs]

    // ---- metadata ----
    int t   = (lane < L) ? timev[(size_t)n * L + lane] : 0;
    int nbv = (lane < L) ? nbr[(size_t)n * L + lane]  : 0;

    // ---- mailbox fill: rows 0..47 via global_load_lds (16B/lane, 8 rows/instr)
    {
        const int soff = (((lane & 7) ^ (lane >> 3)) << 4);   // g-invariant part
        const int rsel = (lane >> 3) << 2;                    // bpermute byte idx
#pragma unroll
        for (int g = 0; g < 6; g++) {
            int nb = __builtin_amdgcn_ds_bpermute(rsel + (g << 5), nbv);
            const char* gp = (const char*)(Hsrc + (size_t)(unsigned)nb * 32)
                             + (soff ^ ((g & 3) << 5));
            gload_lds16(gp, (char*)mbw + (g << 10));
        }
        // rows 48..49: one manual pass (2 rows x 32 dw over 64 lanes)
        int row = 48 + (lane >> 5), d = lane & 31;
        int nb = __builtin_amdgcn_ds_bpermute(row << 2, nbv);
        unsigned int v = Hsrc[(size_t)(unsigned)nb * 32 + d];
        int swzr = (row & 7) ^ (((row >> 3) & 3) << 1);
        mbw[(row << 5) + ((((d >> 2) ^ swzr) << 2) | (d & 3))] = v;
    }

    // ---- tek B-frag prefetch (alpha-independent; hides under rank+softmax)
    short8x bKr[2][4];
#pragma unroll
    for (int kt = 0; kt < 2; kt++)
#pragma unroll
        for (int nt = 0; nt < 4; nt++)
            bKr[kt][nt] = *(const short8x*)(tekP + (c16 + 16 * nt) * 64
                                            + kt * 32 + q4 * 8);

    // ---- last (before rank so lm loads issue early) ----
    unsigned int key2 = (lane < L) ? ((((unsigned)t) << 6) | (unsigned)(63 - lane)) : 0u;
    unsigned int m2 = key2;
#pragma unroll
    for (int s = 32; s; s >>= 1) { unsigned int o2 = __shfl_xor(m2, s); m2 = (o2 > m2) ? o2 : m2; }
    const int last = 63 - (int)(m2 & 63u);
    int nbl = __shfl(nbv, last);                      // last is wave-uniform

    // ---- dh / lm A-frags direct from global (raw bf16, bit-identical) ----
    short8x dhf[2], lmf[2];
#pragma unroll
    for (int kt = 0; kt < 2; kt++) {
        dhf[kt] = *(const short8x*)(Hd16 + (size_t)n * 64 + kt * 32 + q4 * 8);
        lmf[kt] = *(const short8x*)(Hs16 + (size_t)(unsigned)nbl * 64 + kt * 32 + q4 * 8);
    }

    // ---- rank ----
    unsigned int key = (lane < L) ? ((((unsigned)t) << 6) | (unsigned)lane) : 0u;
    int rank = 0;
#pragma unroll
    for (int j = 0; j < L; j++) {
        unsigned int kj = (unsigned int)rli((int)key, j);
        rank += (kj < key) ? 1 : 0;
    }
    int re_o = (lane < L) ? (L - 1 - rank) : lane;   // pad lanes: distinct slots

    // ---- scores + teh via MFMA: D=[dh;lm]·M^T, D_t=[dh]·te^T ----
    f32x4 zero4 = {0.f, 0.f, 0.f, 0.f};
    f32x4 acc_e[4], acc_t[4];
#pragma unroll
    for (int nt = 0; nt < 4; nt++) { acc_e[nt] = zero4; acc_t[nt] = zero4; }
    __builtin_amdgcn_s_setprio(1);
#pragma unroll
    for (int kt = 0; kt < 2; kt++) {
        short8x afr = (c16 & 1) ? lmf[kt] : dhf[kt];
        int cc = kt * 4 + q4;                          // logical 16B chunk
#pragma unroll
        for (int nt = 0; nt < 4; nt++) {
            int row = c16 + 16 * nt;
            int rowc = (row < MROWS) ? row : 0;        // rows >=50 masked later
            int swzr = (rowc & 7) ^ (((rowc >> 3) & 3) << 1);
            short8x bv = *(const short8x*)((const char*)mbw + rowc * 128
                                           + ((cc ^ swzr) << 4));
            acc_e[nt] = __builtin_amdgcn_mfma_f32_16x16x32_bf16(afr, bv, acc_e[nt], 0, 0, 0);
            short8x bt = *(const short8x*)(teP + row * 64 + kt * 32 + q4 * 8);
            acc_t[nt] = __builtin_amdgcn_mfma_f32_16x16x32_bf16(afr, bt, acc_t[nt], 0, 0, 0);
        }
    }
    __builtin_amdgcn_s_setprio(0);
    if (q4 == 0) {
#pragma unroll
        for (int nt = 0; nt < 4; nt++) {
            escf[c16 + 16 * nt]       = acc_e[nt][0];   // e
            escf[64 + c16 + 16 * nt]  = acc_e[nt][1];   // e1
            escf[128 + c16 + 16 * nt] = acc_t[nt][0];   // teh (rank-indexed)
        }
    }
    float e  = escf[lane];
    float e1 = escf[64 + lane];
    float th = escf[128 + re_o];

    e = (e + th) * 0.125f;
    e1 *= 0.125f;
    if (lane >= L) { e = -3e38f; e1 = -3e38f; }

    // ---- dual softmax over neighbors ----
    float mx = e;
#pragma unroll
    for (int s = 32; s; s >>= 1) { float o2 = __shfl_xor(mx, s); mx = (o2 > mx) ? o2 : mx; }
    float ex = __expf(e - mx);
    float sm = ex;
#pragma unroll
    for (int s = 32; s; s >>= 1) sm += __shfl_xor(sm, s);
    float alpha = ex / sm;

    float mx1 = e1;
#pragma unroll
    for (int s = 32; s; s >>= 1) { float o2 = __shfl_xor(mx1, s); mx1 = (o2 > mx1) ? o2 : mx1; }
    float ex1 = __expf(e1 - mx1);
    float sm1 = ex1;
#pragma unroll
    for (int s = 32; s; s >>= 1) sm1 += __shfl_xor(sm1, s);
    float aw = ex1 / sm1;

    // ---- alpha/a1/beta (bf16) into dla ----
    // pad lanes: alpha == aw == 0 exactly -> rows >=50 contribute nothing below
    dla[lane]       = (unsigned short)f2bfbits(alpha);
    dla[64 + lane]  = (unsigned short)f2bfbits(aw);
    dla[128 + re_o] = (unsigned short)f2bfbits(alpha);   // beta[r]: alpha at rank r

    // ---- sums via MFMA: [alpha;a1]·M (conflict-free u16 gathers) + [beta]·tek^T
    f32x4 acc_s[4], acc_k[4];
#pragma unroll
    for (int nt = 0; nt < 4; nt++) { acc_s[nt] = zero4; acc_k[nt] = zero4; }
    __builtin_amdgcn_s_setprio(1);
#pragma unroll
    for (int kt = 0; kt < 2; kt++) {
        short8x aS = *(const short8x*)(dla + (c16 & 1) * 64 + kt * 32 + q4 * 8);
        short8x aB = *(const short8x*)(dla + 128 + kt * 32 + q4 * 8);
        int kr128[8];
#pragma unroll
        for (int i = 0; i < 8; i++) {
            int k = kt * 32 + q4 * 8 + i;
            if (kt) k = (k < MROWS) ? k : (k - 32);   // alpha=0 rows: any finite row
            kr128[i] = k << 7;                        // preserves k&7==i, (k>>3)&3==q4
        }
        const int qx = q4 << 1;                       // swizzle high bits
#pragma unroll
        for (int nt = 0; nt < 4; nt++) {
            int dc = c16 + 16 * nt;
            int tq = (dc >> 3) ^ qx;
            const char* cbase = (const char*)mbw + ((dc & 7) << 1);
            union { short8x v; unsigned short u[8]; } bu;
#pragma unroll
            for (int i = 0; i < 8; i++)
                bu.u[i] = *(const unsigned short*)(cbase + kr128[i] + ((tq ^ i) << 4));
            acc_s[nt] = __builtin_amdgcn_mfma_f32_16x16x32_bf16(aS, bu.v, acc_s[nt], 0, 0, 0);
            acc_k[nt] = __builtin_amdgcn_mfma_f32_16x16x32_bf16(aB, bKr[kt][nt], acc_k[nt], 0, 0, 0);
        }
    }
    __builtin_amdgcn_s_setprio(0);
    // cat = [hl|hs] overlay onto escf (dead after softmax)
    if (q4 == 0) {
#pragma unroll
        for (int nt = 0; nt < 4; nt++) {
            cat[c16 + 16 * nt]      = (unsigned short)f2bfbits(acc_s[nt][0] + acc_k[nt][0]);
            cat[64 + c16 + 16 * nt] = (unsigned short)f2bfbits(acc_s[nt][1]);
        }
    }
    __syncthreads();   // only barrier: epilogue mixes waves' cat rows

    // ---- epilogue: out = elu(cat @ Wg + f) ----
    short8x bfr[4];
#pragma unroll
    for (int tK = 0; tK < 4; tK++)
        bfr[tK] = *(const short8x*)(WgP + (wid * 16 + c16) * 128 + tK * 32 + q4 * 8);

    const unsigned short* catw =
        (const unsigned short*)(lds + (lane & 3) * PW3 + MROWS * 32 + 96);
    f32x4 acc = zero4;
#pragma unroll
    for (int tK = 0; tK < 4; tK++) {
        short8x a = *(const short8x*)(catw + tK * 32 + q4 * 8);
        acc = __builtin_amdgcn_mfma_f32_16x16x32_bf16(a, bfr[tK], acc, 0, 0, 0);
    }
    float r01 = (q4 & 1) ? acc[1] : acc[0];
    float r23 = (q4 & 1) ? acc[3] : acc[2];
    float pv  = (q4 & 2) ? r23 : r01;

    int node = bb * 4 + q4;
    float fres = dst_feat[(size_t)node * D + wid * 16 + c16];
    float oo = pv + fres;
    oo = (oo > 0.f) ? oo : (__expf(oo) - 1.f);
    outp[(size_t)node * D + wid * 16 + c16] = oo;
}

// ---------------- fallback: round-5 monolith (passed, 447us) ---------------
__global__ __launch_bounds__(256) void attn_mono(
    const float* __restrict__ src_feat, const float* __restrict__ dst_feat,
    const float* __restrict__ W_src, const float* __restrict__ W_dst,
    const float* __restrict__ Wg, const float* __restrict__ te,
    const float* __restrict__ tek, const int* __restrict__ nbr,
    const int* __restrict__ timev, float* __restrict__ out)
{
    __shared__ unsigned int ws32[64 * 33];
    __shared__ unsigned int te32[L * 33];
    __shared__ unsigned int mbs[4][L * 33];
    const int tid = threadIdx.x, lane = tid & 63, wid = tid >> 6;
    const int n = blockIdx.x * 4 + wid;
    {
        const float2* Wf2 = (const float2*)W_src;
        const float2* Te2 = (const float2*)te;
        for (int idx = tid; idx < 2048; idx += 256) {
            float2 w = Wf2[idx];
            ws32[(idx >> 5) * 33 + (idx & 31)] = packbf(w.x, w.y);
            if (idx < 1600) {
                float2 t2 = Te2[idx];
                te32[(idx >> 5) * 33 + (idx & 31)] = packbf(t2.x, t2.y);
            }
        }
    }
    __syncthreads();
    int t  = (lane < L) ? timev[(size_t)n * L + lane] : 0;
    int nb = (lane < L) ? nbr[(size_t)n * L + lane]  : 0;
    unsigned int key  = (lane < L) ? ((((unsigned)t) << 6) | (unsigned)lane) : 0u;
    unsigned int key2 = (lane < L) ? ((((unsigned)t) << 6) | (unsigned)(63 - lane)) : 0u;
    int rank = 0;
#pragma unroll
    for (int j = 0; j < L; j++) {
        unsigned int kj = (unsigned int)rli((int)key, j);
        rank += (kj < key) ? 1 : 0;
    }
    int re_o = (lane < L) ? (L - 1 - rank) : 0;
    unsigned int m2 = key2;
#pragma unroll
    for (int s = 32; s; s >>= 1) { unsigned int o2 = __shfl_xor(m2, s); m2 = (o2 > m2) ? o2 : m2; }
    const int last = 63 - (int)(m2 & 63u);
    const int rr = (lane < L) ? lane : (L - 1);
    float f = dst_feat[(size_t)n * D + lane];
    float dh;
    {
        float b0 = 0.f, b1 = 0.f, b2 = 0.f, b3 = 0.f;
#pragma unroll
        for (int k = 0; k < 64; k += 4) {
            b0 += rl(f, k + 0) * W_dst[(k + 0) * 64 + lane];
            b1 += rl(f, k + 1) * W_dst[(k + 1) * 64 + lane];
            b2 += rl(f, k + 2) * W_dst[(k + 2) * 64 + lane];
            b3 += rl(f, k + 3) * W_dst[(k + 3) * 64 + lane];
        }
        dh = (b0 + b1) + (b2 + b3);
    }
    float v1;
    {
        float b0 = 0.f, b1 = 0.f, b2 = 0.f, b3 = 0.f;
#pragma unroll
        for (int j = 0; j < 32; j += 2) {
            unsigned int u0 = ws32[lane * 33 + j];
            unsigned int u1 = ws32[lane * 33 + j + 1];
            b0 += lof(u0) * rl(dh, 2 * j + 0);
            b1 += hif(u0) * rl(dh, 2 * j + 1);
            b2 += lof(u1) * rl(dh, 2 * j + 2);
            b3 += hif(u1) * rl(dh, 2 * j + 3);
        }
        v1 = (b0 + b1) + (b2 + b3);
    }
    unsigned int* mbw = mbs[wid];
    {
        const float2* src2 = (const float2*)src_feat;
        int half = lane >> 5, col = lane & 31;
#pragma unroll
        for (int l = 0; l < L; l += 2) {
            int ra = rli(nb, l), rb = rli(nb, l + 1);
            int r = half ? rb : ra;
            float2 v = src2[(size_t)r * 32 + col];
            mbw[(l + half) * 33 + col] = packbf(v.x, v.y);
        }
    }
    __syncthreads();
    unsigned int ul = mbw[last * 33 + (lane >> 1)];
    float rlast = (lane & 1) ? hif(ul) : lof(ul);
    float g;
    {
        float b0 = 0.f, b1 = 0.f, b2 = 0.f, b3 = 0.f;
#pragma unroll
        for (int k = 0; k < 64; k += 4) {
            b0 += rl(rlast, k + 0) * W_src[(k + 0) * 64 + lane];
            b1 += rl(rlast, k + 1) * W_src[(k + 1) * 64 + lane];
            b2 += rl(rlast, k + 2) * W_src[(k + 2) * 64 + lane];
            b3 += rl(rlast, k + 3) * W_src[(k + 3) * 64 + lane];
        }
        g = (b0 + b1) + (b2 + b3);
    }
    float v2;
    {
        float b0 = 0.f, b1 = 0.f, b2 = 0.f, b3 = 0.f;
#pragma unroll
        for (int j = 0; j < 32; j += 2) {
            unsigned int u0 = ws32[lane * 33 + j];
            unsigned int u1 = ws32[lane * 33 + j + 1];
            b0 += lof(u0) * rl(g, 2 * j + 0);
            b1 += hif(u0) * rl(g, 2 * j + 1);
            b2 += lof(u1) * rl(g, 2 * j + 2);
            b3 += hif(u1) * rl(g, 2 * j + 3);
        }
        v2 = (b0 + b1) + (b2 + b3);
    }
    float teh;
    {
        float b0 = 0.f, b1 = 0.f, b2 = 0.f, b3 = 0.f;
#pragma unroll
        for (int j = 0; j < 32; j += 2) {
            unsigned int u0 = te32[rr * 33 + j];
            unsigned int u1 = te32[rr * 33 + j + 1];
            b0 += lof(u0) * rl(dh, 2 * j + 0);
            b1 += hif(u0) * rl(dh, 2 * j + 1);
            b2 += lof(u1) * rl(dh, 2 * j + 2);
            b3 += hif(u1) * rl(dh, 2 * j + 3);
        }
        teh = (b0 + b1) + (b2 + b3);
    }
    float e, e1;
    {
        float ea = 0.f, eb = 0.f, qa = 0.f, qb = 0.f;
#pragma unroll
        for (int j = 0; j < 32; j += 2) {
            unsigned int u0 = mbw[rr * 33 + j];
            unsigned int u1 = mbw[rr * 33 + j + 1];
            float m0 = lof(u0), m1 = hif(u0), m2f = lof(u1), m3 = hif(u1);
            ea += m0 * rl(v1, 2 * j + 0) + m1 * rl(v1, 2 * j + 1);
            eb += m2f * rl(v1, 2 * j + 2) + m3 * rl(v1, 2 * j + 3);
            qa += m0 * rl(v2, 2 * j + 0) + m1 * rl(v2, 2 * j + 1);
            qb += m2f * rl(v2, 2 * j + 2) + m3 * rl(v2, 2 * j + 3);
        }
        e = ea + eb; e1 = qa + qb;
    }
    e = (e + __shfl(teh, re_o)) * 0.125f;
    e1 *= 0.125f;
    if (lane >= L) { e = -3e38f; e1 = -3e38f; }
    float mx = e;
#pragma unroll
    for (int s = 32; s; s >>= 1) { float o2 = __shfl_xor(mx, s); mx = (o2 > mx) ? o2 : mx; }
    float ex = __expf(e - mx);
    float sm = ex;
#pragma unroll
    for (int s = 32; s; s >>= 1) sm += __shfl_xor(sm, s);
    float alpha = ex / sm;
    float mx1 = e1;
#pragma unroll
    for (int s = 32; s; s >>= 1) { float o2 = __shfl_xor(mx1, s); mx1 = (o2 > mx1) ? o2 : mx1; }
    float ex1 = __expf(e1 - mx1);
    float sm1 = ex1;
#pragma unroll
    for (int s = 32; s; s >>= 1) sm1 += __shfl_xor(sm1, s);
    float aw = ex1 / sm1;
    float sl, ss, tacc;
    {
        float sA = 0.f, sB = 0.f, hA = 0.f, hB = 0.f, tA = 0.f, tB = 0.f;
        int hcol = lane >> 1, odd = lane & 1;
#pragma unroll
        for (int l = 0; l < L; l += 2) {
            float saA = rl(alpha, l),     s1A = rl(aw, l);
            float saB = rl(alpha, l + 1), s1B = rl(aw, l + 1);
            int   roA = rli(re_o, l),     roB = rli(re_o, l + 1);
            unsigned int uA = mbw[(l + 0) * 33 + hcol];
            unsigned int uB = mbw[(l + 1) * 33 + hcol];
            float mA = odd ? hif(uA) : lof(uA);
            float mB = odd ? hif(uB) : lof(uB);
            sA += saA * mA; hA += s1A * mA; tA += saA * tek[roA * 64 + lane];
            sB += saB * mB; hB += s1B * mB; tB += saB * tek[roB * 64 + lane];
        }
        sl = sA + sB; ss = hA + hB; tacc = tA + tB;
    }
    float hl, hs;
    {
        float lA = 0.f, lB = 0.f, sA = 0.f, sB = 0.f;
#pragma unroll
        for (int k = 0; k < 64; k += 2) {
            float w0 = W_src[(k + 0) * 64 + lane];
            float w1 = W_src[(k + 1) * 64 + lane];
            lA += rl(sl, k + 0) * w0; sA += rl(ss, k + 0) * w0;
            lB += rl(sl, k + 1) * w1; sB += rl(ss, k + 1) * w1;
        }
        hl = tacc + lA + lB; hs = sA + sB;
    }
    float o;
    {
        float o0 = 0.f, o1 = 0.f, o2 = 0.f, o3 = 0.f;
#pragma unroll
        for (int k = 0; k < 64; k += 2) {
            o0 += rl(hl, k + 0) * Wg[(k + 0) * 64 + lane];
            o1 += rl(hl, k + 1) * Wg[(k + 1) * 64 + lane];
            o2 += rl(hs, k + 0) * Wg[(k + 64) * 64 + lane];
            o3 += rl(hs, k + 1) * Wg[(k + 65) * 64 + lane];
        }
        o = f + (o0 + o1) + (o2 + o3);
    }
    o = (o > 0.f) ? o : (__expf(o) - 1.f);
    out[(size_t)n * D + lane] = o;
}

extern "C" void kernel_launch(void* const* d_in, const int* in_sizes, int n_in,
                              void* d_out, int out_size, void* d_ws, size_t ws_size,
                              hipStream_t stream) {
    const float* user_feat = (const float*)d_in[0];
    const float* item_feat = (const float*)d_in[1];
    const float* W_u  = (const float*)d_in[2];
    const float* W_i  = (const float*)d_in[3];
    const float* Wg_u = (const float*)d_in[4];
    const float* Wg_i = (const float*)d_in[5];
    const float* i_te   = (const float*)d_in[6];
    const float* i_te_k = (const float*)d_in[7];
    const float* u_te   = (const float*)d_in[8];
    const float* u_te_k = (const float*)d_in[9];
    const int* item_nbr  = (const int*)d_in[10];
    const int* item_time = (const int*)d_in[11];
    const int* user_nbr  = (const int*)d_in[12];
    const int* user_time = (const int*)d_in[13];
    (void)in_sizes; (void)n_in; (void)out_size;

    float* outp = (float*)d_out;
    const size_t H_BYTES = (size_t)(NUM_U + NUM_I) * 32 * 4;            // 6.4 MB
    const size_t NEED = H_BYTES + 2 * 16384 + 4 * 8192;                 // +64 KB aux

    if (ws_size >= NEED) {
        unsigned int* Hp = (unsigned int*)d_ws;
        unsigned char* aux = (unsigned char*)d_ws + H_BYTES;
        unsigned short* WgPi = (unsigned short*)(aux);
        unsigned short* WgPu = (unsigned short*)(aux + 16384);
        unsigned short* tePi = (unsigned short*)(aux + 32768);
        unsigned short* tePu = (unsigned short*)(aux + 40960);
        unsigned short* tkPi = (unsigned short*)(aux + 49152);
        unsigned short* tkPu = (unsigned short*)(aux + 57344);

        prep<<<GEMM_BLKS + 16, 256, 0, stream>>>(user_feat, item_feat, W_u, W_i,
                                       Wg_i, Wg_u, i_te, u_te, i_te_k, u_te_k,
                                       Hp, WgPi, WgPu, tePi, tePu, tkPi, tkPu);
        attn_fused<<<(NUM_I + NUM_U) / 4, 256, 0, stream>>>(
            Hp, user_feat, item_feat, WgPi, WgPu, tePi, tePu, tkPi, tkPu,
            item_nbr, item_time, user_nbr, user_time, outp);
    } else {
        attn_mono<<<NUM_I / 4, 256, 0, stream>>>(
            user_feat, item_feat, W_u, W_i, Wg_i, i_te, i_te_k,
            item_nbr, item_time, outp + (size_t)NUM_U * D);
        attn_mono<<<NUM_U / 4, 256, 0, stream>>>(
            item_feat, user_feat, W_i, W_u, Wg_u, u_te, u_te_k,
            user_nbr, user_time, outp);
    }
}

// Round 6
// 231.697 us; speedup vs baseline: 1.0903x; 1.0903x over previous
//
#include <hip/hip_runtime.h>
#include <stdint.h>

#define D   64
#define L   50
#define NUM_U 30000
#define NUM_I 20000
#define MROWS 50
#define REG_OFF 1600                  // region base (dw): mailbox is 1600 dw
#define PW3 1696                      // 1600 mailbox + 96-dw u16 region = 27136 B/block
#define GEMM_BLKS 782                 // 3125 row-tiles of 16, 4 waves/block

// r9: 241.5 (attn 144). r10: global gathers REGRESSED. r11: DMA fill +
//     chunk-XOR swizzle: attn 137.7. r12: prep->MFMA; residue = harness.
// r13: reg-prefetch REGRESSED (scratch spill, WRITE 12.5->112MB); extended
//     swizzle VALIDATED (conflicts 7.7M->0.9M).
// r14: FAILED absmax 0.196: float<->u16 overlay in one LDS region -> TBAA
//     no-alias -> compiler reorders/skips lgkmcnt across phases. Same-type
//     u16 overlays (r9-r13) are safe; mixed-type at same address is not.
// r15: keep 27136B/6 blocks/CU, but NO float LDS: e/e1/teh extracted from
//     accumulators via 12 bpermute + 4-way select (slot j = acc[j>>4][reg]
//     on lane j&15 -- same mapping the escf write/read implemented).
//     Region is u16-only: dh|lm -> alpha|a1|beta -> cat.

typedef __attribute__((ext_vector_type(8))) short short8x;   // 8 bf16
typedef __attribute__((ext_vector_type(4))) float f32x4;     // MFMA acc

__device__ __forceinline__ float lof(unsigned int u) {
    union { unsigned int i; float f; } v; v.i = u << 16; return v.f;
}
__device__ __forceinline__ float hif(unsigned int u) {
    union { unsigned int i; float f; } v; v.i = u & 0xffff0000u; return v.f;
}
__device__ __forceinline__ unsigned int f2bfbits(float f) {
    union { float f; unsigned int i; } v; v.f = f;
    return (v.i + 0x7fffu + ((v.i >> 16) & 1u)) >> 16;   // RNE
}
__device__ __forceinline__ unsigned int packbf(float a, float b) {
    return f2bfbits(a) | (f2bfbits(b) << 16);
}
__device__ __forceinline__ float rl(float v, int l) {
    return __int_as_float(__builtin_amdgcn_readlane(__float_as_int(v), l));
}
__device__ __forceinline__ int rli(int v, int l) {
    return __builtin_amdgcn_readlane(v, l);
}
__device__ __forceinline__ void gload_lds16(const void* g, void* l) {
    __builtin_amdgcn_global_load_lds(
        (const __attribute__((address_space(1))) unsigned int*)g,
        (__attribute__((address_space(3))) unsigned int*)l, 16, 0, 0);
}
// select v[idx] for 2-bit idx via cndmask tree
__device__ __forceinline__ float sel4(float v0, float v1, float v2, float v3, int idx) {
    float a = (idx & 1) ? v1 : v0;
    float b = (idx & 1) ? v3 : v2;
    return (idx & 2) ? b : a;
}

// ---------------- K1: fused prep: H = feat@W (MFMA) + bf16 weight packing ---
__global__ __launch_bounds__(256) void prep(
    const float* __restrict__ user_feat, const float* __restrict__ item_feat,
    const float* __restrict__ W_u, const float* __restrict__ W_i,
    const float* __restrict__ Wg_i, const float* __restrict__ Wg_u,
    const float* __restrict__ te_i, const float* __restrict__ te_u,
    const float* __restrict__ tk_i, const float* __restrict__ tk_u,
    unsigned int* __restrict__ H,
    unsigned short* __restrict__ WgPi, unsigned short* __restrict__ WgPu,
    unsigned short* __restrict__ tePi, unsigned short* __restrict__ tePu,
    unsigned short* __restrict__ tkPi, unsigned short* __restrict__ tkPu)
{
    const int tid = threadIdx.x;
    if (blockIdx.x < GEMM_BLKS) {
        const int lane = tid & 63, wid = tid >> 6;
        const int tile = blockIdx.x * 4 + wid;            // 16 rows per tile
        if (tile >= 3125) return;                         // 3125*16 = 50000 exact
        const int r0 = tile * 16;
        const float* src; const float* W;
        if (r0 < NUM_U) { src = user_feat + (size_t)r0 * D;            W = W_u; }
        else            { src = item_feat + (size_t)(r0 - NUM_U) * D;  W = W_i; }
        const int q4 = lane >> 4, c16 = lane & 15;

        // B-frags: feat rows. B[n=c16][k=kt*32+q4*8+j], coalesced float4 pairs.
        short8x bf[2];
#pragma unroll
        for (int kt = 0; kt < 2; kt++) {
            const float* fp = src + c16 * D + kt * 32 + q4 * 8;
            float4 x = *(const float4*)fp;
            float4 y = *(const float4*)(fp + 4);
            union { short8x v; unsigned int u[4]; } t2;
            t2.u[0] = packbf(x.x, x.y); t2.u[1] = packbf(x.z, x.w);
            t2.u[2] = packbf(y.x, y.y); t2.u[3] = packbf(y.z, y.w);
            bf[kt] = t2.v;
        }
        // A-frags: W^T. A[m=c16+16mt][k] = W[k][c16+16mt]; W is 16KB, L1-hot.
        f32x4 zero4 = {0.f, 0.f, 0.f, 0.f};
        f32x4 acc[4];
#pragma unroll
        for (int mt = 0; mt < 4; mt++) acc[mt] = zero4;
#pragma unroll
        for (int kt = 0; kt < 2; kt++) {
#pragma unroll
            for (int mt = 0; mt < 4; mt++) {
                union { short8x v; unsigned short u[8]; } a;
#pragma unroll
                for (int j = 0; j < 8; j++)
                    a.u[j] = (unsigned short)f2bfbits(
                        W[(kt * 32 + q4 * 8 + j) * D + c16 + 16 * mt]);
                acc[mt] = __builtin_amdgcn_mfma_f32_16x16x32_bf16(a.v, bf[kt], acc[mt], 0, 0, 0);
            }
        }
        // D[m][n]: col(c16) = feat row n, reg row = m = q4*4+r -> H col.
        unsigned int* Hrow = H + (size_t)(r0 + c16) * 32;
#pragma unroll
        for (int mt = 0; mt < 4; mt++) {
            uint2 pk;
            pk.x = packbf(acc[mt][0], acc[mt][1]);
            pk.y = packbf(acc[mt][2], acc[mt][3]);
            *(uint2*)(Hrow + 8 * mt + 2 * q4) = pk;
        }
    } else {
        int gid = (blockIdx.x - GEMM_BLKS) * 256 + tid;   // 16 blocks, gs=4096
        for (int idx = gid; idx < 8192; idx += 4096) {
            int n = idx >> 7, k = idx & 127;
            WgPi[idx] = (unsigned short)f2bfbits(Wg_i[k * 64 + n]);
            WgPu[idx] = (unsigned short)f2bfbits(Wg_u[k * 64 + n]);
        }
        {
            int idx = gid;                                // 4096 elements, 1 iter
            int r = idx >> 6, k = idx & 63;
            tePi[idx] = (r < L) ? (unsigned short)f2bfbits(te_i[r * 64 + k]) : 0;
            tePu[idx] = (r < L) ? (unsigned short)f2bfbits(te_u[r * 64 + k]) : 0;
            int d = idx >> 6, rr = idx & 63;
            tkPi[idx] = (rr < L) ? (unsigned short)f2bfbits(tk_i[rr * 64 + d]) : 0;
            tkPu[idx] = (rr < L) ? (unsigned short)f2bfbits(tk_u[rr * 64 + d]) : 0;
        }
    }
}

// ---------------- K2: fused attention, both sides, MFMA math ----------------
// Swizzle: LDS[row][pc] = G[row][pc ^ swz(row)], swz(row) = (row&7) ^
// (((row>>3)&3)<<1). Sums gather conflict-free; scores b128 <=2-way.
// u16-only 96-dw region: {dh|lm} -> {alpha|a1|beta} -> {cat}.
__global__ __launch_bounds__(256, 6) void attn_fused(
    const unsigned int* __restrict__ H,
    const float* __restrict__ user_feat, const float* __restrict__ item_feat,
    const unsigned short* __restrict__ WgPi, const unsigned short* __restrict__ WgPu,
    const unsigned short* __restrict__ tePi, const unsigned short* __restrict__ tePu,
    const unsigned short* __restrict__ tkPi, const unsigned short* __restrict__ tkPu,
    const int* __restrict__ item_nbr, const int* __restrict__ item_time,
    const int* __restrict__ user_nbr, const int* __restrict__ user_time,
    float* __restrict__ out)
{
    __shared__ unsigned int lds[4 * PW3];   // 27136 B -> 6 blocks/CU

    const int tid = threadIdx.x, lane = tid & 63, wid = tid >> 6;
    const bool iside = blockIdx.x < (NUM_I / 4);
    const int bb = iside ? blockIdx.x : blockIdx.x - NUM_I / 4;
    const int n = bb * 4 + wid;
    const int src_base = iside ? 0 : NUM_U;
    const int dst_base = iside ? NUM_U : 0;
    const float* dst_feat = iside ? item_feat : user_feat;
    const unsigned short* WgP  = iside ? WgPi : WgPu;
    const unsigned short* teP  = iside ? tePi : tePu;
    const unsigned short* tekP = iside ? tkPi : tkPu;
    const int* nbr   = iside ? item_nbr  : user_nbr;
    const int* timev = iside ? item_time : user_time;
    float* outp = out + (iside ? (size_t)NUM_U * D : 0);

    const int q4 = lane >> 4, c16 = lane & 15;

    const unsigned int*   Hsrc = H + (size_t)src_base * 32;
    const unsigned short* Hs16 = (const unsigned short*)H + (size_t)src_base * 64;
    const unsigned short* Hd16 = (const unsigned short*)H + (size_t)dst_base * 64;

    // per-wave LDS slices
    unsigned int*   wld = lds + wid * PW3;
    unsigned int*   mbw = wld;                             // 50 rows x 32 dw, swizzled
    unsigned short* dla = (unsigned short*)(wld + REG_OFF);    // u16-only region
    unsigned short* cat = (unsigned short*)(wld + REG_OFF);    // overlay (u16, same type)

    // ---- metadata ----
    int t   = (lane < L) ? timev[(size_t)n * L + lane] : 0;
    int nbv = (lane < L) ? nbr[(size_t)n * L + lane]  : 0;

    // ---- mailbox fill: rows 0..47 via global_load_lds (16B/lane, 8 rows/instr)
    {
        const int soff = (((lane & 7) ^ (lane >> 3)) << 4);   // g-invariant part
        const int rsel = (lane >> 3) << 2;                    // bpermute byte idx
#pragma unroll
        for (int g = 0; g < 6; g++) {
            int nb = __builtin_amdgcn_ds_bpermute(rsel + (g << 5), nbv);
            const char* gp = (const char*)(Hsrc + (size_t)(unsigned)nb * 32)
                             + (soff ^ ((g & 3) << 5));
            gload_lds16(gp, (char*)mbw + (g << 10));
        }
        // rows 48..49: one manual pass (2 rows x 32 dw over 64 lanes)
        int row = 48 + (lane >> 5), d = lane & 31;
        int nb = __builtin_amdgcn_ds_bpermute(row << 2, nbv);
        unsigned int v = Hsrc[(size_t)(unsigned)nb * 32 + d];
        int swzr = (row & 7) ^ (((row >> 3) & 3) << 1);
        mbw[(row << 5) + ((((d >> 2) ^ swzr) << 2) | (d & 3))] = v;
    }

    // ---- last (before rank so dh/lm loads issue early, short liveness) ----
    unsigned int key2 = (lane < L) ? ((((unsigned)t) << 6) | (unsigned)(63 - lane)) : 0u;
    unsigned int m2 = key2;
#pragma unroll
    for (int s = 32; s; s >>= 1) { unsigned int o2 = __shfl_xor(m2, s); m2 = (o2 > m2) ? o2 : m2; }
    const int last = 63 - (int)(m2 & 63u);
    int nbl = __shfl(nbv, last);                      // last is wave-uniform
    unsigned short dh_u = Hd16[(size_t)n * 64 + lane];              // 2 u16 loads,
    unsigned short lm_u = Hs16[(size_t)(unsigned)nbl * 64 + lane];  // hide under rank

    // ---- rank ----
    unsigned int key = (lane < L) ? ((((unsigned)t) << 6) | (unsigned)lane) : 0u;
    int rank = 0;
#pragma unroll
    for (int j = 0; j < L; j++) {
        unsigned int kj = (unsigned int)rli((int)key, j);
        rank += (kj < key) ? 1 : 0;
    }
    int re_o = (lane < L) ? (L - 1 - rank) : lane;   // pad lanes: distinct slots

    // ---- region phase 0: dh|lm (raw bf16, bit-identical) ----
    dla[lane]      = dh_u;
    dla[64 + lane] = lm_u;

    // ---- scores + teh via MFMA: D=[dh;lm]·M^T, D_t=[dh]·te^T ----
    f32x4 zero4 = {0.f, 0.f, 0.f, 0.f};
    f32x4 acc_e[4], acc_t[4];
#pragma unroll
    for (int nt = 0; nt < 4; nt++) { acc_e[nt] = zero4; acc_t[nt] = zero4; }
    __builtin_amdgcn_s_setprio(1);
#pragma unroll
    for (int kt = 0; kt < 2; kt++) {
        short8x afr = *(const short8x*)(dla + (c16 & 1) * 64 + kt * 32 + q4 * 8);
        int cc = kt * 4 + q4;                          // logical 16B chunk
#pragma unroll
        for (int nt = 0; nt < 4; nt++) {
            int row = c16 + 16 * nt;
            int rowc = (row < MROWS) ? row : 0;        // rows >=50 masked later
            int swzr = (rowc & 7) ^ (((rowc >> 3) & 3) << 1);
            short8x bv = *(const short8x*)((const char*)mbw + rowc * 128
                                           + ((cc ^ swzr) << 4));
            acc_e[nt] = __builtin_amdgcn_mfma_f32_16x16x32_bf16(afr, bv, acc_e[nt], 0, 0, 0);
            short8x bt = *(const short8x*)(teP + row * 64 + kt * 32 + q4 * 8);
            acc_t[nt] = __builtin_amdgcn_mfma_f32_16x16x32_bf16(afr, bt, acc_t[nt], 0, 0, 0);
        }
    }
    __builtin_amdgcn_s_setprio(0);

    // ---- extract e/e1/teh from accumulators (no LDS): slot j lives on lane
    // j&15 (q4==0 rows 0/1 = regs 0/1), register index nt = j>>4.
    float eN0  = __shfl(acc_e[0][0], c16), eN1  = __shfl(acc_e[1][0], c16);
    float eN2  = __shfl(acc_e[2][0], c16), eN3  = __shfl(acc_e[3][0], c16);
    float f1N0 = __shfl(acc_e[0][1], c16), f1N1 = __shfl(acc_e[1][1], c16);
    float f1N2 = __shfl(acc_e[2][1], c16), f1N3 = __shfl(acc_e[3][1], c16);
    int rsrc = re_o & 15;
    float tN0 = __shfl(acc_t[0][0], rsrc), tN1 = __shfl(acc_t[1][0], rsrc);
    float tN2 = __shfl(acc_t[2][0], rsrc), tN3 = __shfl(acc_t[3][0], rsrc);
    float e  = sel4(eN0, eN1, eN2, eN3, q4);
    float e1 = sel4(f1N0, f1N1, f1N2, f1N3, q4);
    float th = sel4(tN0, tN1, tN2, tN3, (re_o >> 4) & 3);

    e = (e + th) * 0.125f;
    e1 *= 0.125f;
    if (lane >= L) { e = -3e38f; e1 = -3e38f; }

    // ---- dual softmax over neighbors ----
    float mx = e;
#pragma unroll
    for (int s = 32; s; s >>= 1) { float o2 = __shfl_xor(mx, s); mx = (o2 > mx) ? o2 : mx; }
    float ex = __expf(e - mx);
    float sm = ex;
#pragma unroll
    for (int s = 32; s; s >>= 1) sm += __shfl_xor(sm, s);
    float alpha = ex / sm;

    float mx1 = e1;
#pragma unroll
    for (int s = 32; s; s >>= 1) { float o2 = __shfl_xor(mx1, s); mx1 = (o2 > mx1) ? o2 : mx1; }
    float ex1 = __expf(e1 - mx1);
    float sm1 = ex1;
#pragma unroll
    for (int s = 32; s; s >>= 1) sm1 += __shfl_xor(sm1, s);
    float aw = ex1 / sm1;

    // ---- region phase 1: alpha|a1|beta (bf16, u16-only overlay) ----
    // pad lanes: alpha == aw == 0 exactly -> rows >=50 contribute nothing below
    dla[lane]       = (unsigned short)f2bfbits(alpha);
    dla[64 + lane]  = (unsigned short)f2bfbits(aw);
    dla[128 + re_o] = (unsigned short)f2bfbits(alpha);   // beta[r]: alpha at rank r

    // ---- sums via MFMA: [alpha;a1]·M (conflict-free u16 gathers) + [beta]·tek^T
    f32x4 acc_s[4], acc_k[4];
#pragma unroll
    for (int nt = 0; nt < 4; nt++) { acc_s[nt] = zero4; acc_k[nt] = zero4; }
    __builtin_amdgcn_s_setprio(1);
#pragma unroll
    for (int kt = 0; kt < 2; kt++) {
        short8x aS = *(const short8x*)(dla + (c16 & 1) * 64 + kt * 32 + q4 * 8);
        short8x aB = *(const short8x*)(dla + 128 + kt * 32 + q4 * 8);
        int kr128[8];
#pragma unroll
        for (int i = 0; i < 8; i++) {
            int k = kt * 32 + q4 * 8 + i;
            if (kt) k = (k < MROWS) ? k : (k - 32);   // alpha=0 rows: any finite row
            kr128[i] = k << 7;                        // preserves k&7==i, (k>>3)&3==q4
        }
        const int qx = q4 << 1;                       // swizzle high bits
#pragma unroll
        for (int nt = 0; nt < 4; nt++) {
            int dc = c16 + 16 * nt;
            int tq = (dc >> 3) ^ qx;
            const char* cbase = (const char*)mbw + ((dc & 7) << 1);
            union { short8x v; unsigned short u[8]; } bu;
#pragma unroll
            for (int i = 0; i < 8; i++)
                bu.u[i] = *(const unsigned short*)(cbase + kr128[i] + ((tq ^ i) << 4));
            acc_s[nt] = __builtin_amdgcn_mfma_f32_16x16x32_bf16(aS, bu.v, acc_s[nt], 0, 0, 0);
            short8x bK = *(const short8x*)(tekP + dc * 64 + kt * 32 + q4 * 8);
            acc_k[nt] = __builtin_amdgcn_mfma_f32_16x16x32_bf16(aB, bK, acc_k[nt], 0, 0, 0);
        }
    }
    __builtin_amdgcn_s_setprio(0);
    // ---- region phase 2: cat = [hl|hs] (u16 overlay, same type) ----
    if (q4 == 0) {
#pragma unroll
        for (int nt = 0; nt < 4; nt++) {
            cat[c16 + 16 * nt]      = (unsigned short)f2bfbits(acc_s[nt][0] + acc_k[nt][0]);
            cat[64 + c16 + 16 * nt] = (unsigned short)f2bfbits(acc_s[nt][1]);
        }
    }
    __syncthreads();   // only barrier: epilogue mixes waves' cat rows

    // ---- epilogue: out = elu(cat @ Wg + f) ----
    short8x bfr[4];
#pragma unroll
    for (int tK = 0; tK < 4; tK++)
        bfr[tK] = *(const short8x*)(WgP + (wid * 16 + c16) * 128 + tK * 32 + q4 * 8);

    const unsigned short* catw =
        (const unsigned short*)(lds + (lane & 3) * PW3 + REG_OFF);
    f32x4 acc = zero4;
#pragma unroll
    for (int tK = 0; tK < 4; tK++) {
        short8x a = *(const short8x*)(catw + tK * 32 + q4 * 8);
        acc = __builtin_amdgcn_mfma_f32_16x16x32_bf16(a, bfr[tK], acc, 0, 0, 0);
    }
    float r01 = (q4 & 1) ? acc[1] : acc[0];
    float r23 = (q4 & 1) ? acc[3] : acc[2];
    float pv  = (q4 & 2) ? r23 : r01;

    int node = bb * 4 + q4;
    float fres = dst_feat[(size_t)node * D + wid * 16 + c16];
    float oo = pv + fres;
    oo = (oo > 0.f) ? oo : (__expf(oo) - 1.f);
    outp[(size_t)node * D + wid * 16 + c16] = oo;
}

// ---------------- fallback: round-5 monolith (passed, 447us) ---------------
__global__ __launch_bounds__(256) void attn_mono(
    const float* __restrict__ src_feat, const float* __restrict__ dst_feat,
    const float* __restrict__ W_src, const float* __restrict__ W_dst,
    const float* __restrict__ Wg, const float* __restrict__ te,
    const float* __restrict__ tek, const int* __restrict__ nbr,
    const int* __restrict__ timev, float* __restrict__ out)
{
    __shared__ unsigned int ws32[64 * 33];
    __shared__ unsigned int te32[L * 33];
    __shared__ unsigned int mbs[4][L * 33];
    const int tid = threadIdx.x, lane = tid & 63, wid = tid >> 6;
    const int n = blockIdx.x * 4 + wid;
    {
        const float2* Wf2 = (const float2*)W_src;
        const float2* Te2 = (const float2*)te;
        for (int idx = tid; idx < 2048; idx += 256) {
            float2 w = Wf2[idx];
            ws32[(idx >> 5) * 33 + (idx & 31)] = packbf(w.x, w.y);
            if (idx < 1600) {
                float2 t2 = Te2[idx];
                te32[(idx >> 5) * 33 + (idx & 31)] = packbf(t2.x, t2.y);
            }
        }
    }
    __syncthreads();
    int t  = (lane < L) ? timev[(size_t)n * L + lane] : 0;
    int nb = (lane < L) ? nbr[(size_t)n * L + lane]  : 0;
    unsigned int key  = (lane < L) ? ((((unsigned)t) << 6) | (unsigned)lane) : 0u;
    unsigned int key2 = (lane < L) ? ((((unsigned)t) << 6) | (unsigned)(63 - lane)) : 0u;
    int rank = 0;
#pragma unroll
    for (int j = 0; j < L; j++) {
        unsigned int kj = (unsigned int)rli((int)key, j);
        rank += (kj < key) ? 1 : 0;
    }
    int re_o = (lane < L) ? (L - 1 - rank) : 0;
    unsigned int m2 = key2;
#pragma unroll
    for (int s = 32; s; s >>= 1) { unsigned int o2 = __shfl_xor(m2, s); m2 = (o2 > m2) ? o2 : m2; }
    const int last = 63 - (int)(m2 & 63u);
    const int rr = (lane < L) ? lane : (L - 1);
    float f = dst_feat[(size_t)n * D + lane];
    float dh;
    {
        float b0 = 0.f, b1 = 0.f, b2 = 0.f, b3 = 0.f;
#pragma unroll
        for (int k = 0; k < 64; k += 4) {
            b0 += rl(f, k + 0) * W_dst[(k + 0) * 64 + lane];
            b1 += rl(f, k + 1) * W_dst[(k + 1) * 64 + lane];
            b2 += rl(f, k + 2) * W_dst[(k + 2) * 64 + lane];
            b3 += rl(f, k + 3) * W_dst[(k + 3) * 64 + lane];
        }
        dh = (b0 + b1) + (b2 + b3);
    }
    float v1;
    {
        float b0 = 0.f, b1 = 0.f, b2 = 0.f, b3 = 0.f;
#pragma unroll
        for (int j = 0; j < 32; j += 2) {
            unsigned int u0 = ws32[lane * 33 + j];
            unsigned int u1 = ws32[lane * 33 + j + 1];
            b0 += lof(u0) * rl(dh, 2 * j + 0);
            b1 += hif(u0) * rl(dh, 2 * j + 1);
            b2 += lof(u1) * rl(dh, 2 * j + 2);
            b3 += hif(u1) * rl(dh, 2 * j + 3);
        }
        v1 = (b0 + b1) + (b2 + b3);
    }
    unsigned int* mbw = mbs[wid];
    {
        const float2* src2 = (const float2*)src_feat;
        int half = lane >> 5, col = lane & 31;
#pragma unroll
        for (int l = 0; l < L; l += 2) {
            int ra = rli(nb, l), rb = rli(nb, l + 1);
            int r = half ? rb : ra;
            float2 v = src2[(size_t)r * 32 + col];
            mbw[(l + half) * 33 + col] = packbf(v.x, v.y);
        }
    }
    __syncthreads();
    unsigned int ul = mbw[last * 33 + (lane >> 1)];
    float rlast = (lane & 1) ? hif(ul) : lof(ul);
    float g;
    {
        float b0 = 0.f, b1 = 0.f, b2 = 0.f, b3 = 0.f;
#pragma unroll
        for (int k = 0; k < 64; k += 4) {
            b0 += rl(rlast, k + 0) * W_src[(k + 0) * 64 + lane];
            b1 += rl(rlast, k + 1) * W_src[(k + 1) * 64 + lane];
            b2 += rl(rlast, k + 2) * W_src[(k + 2) * 64 + lane];
            b3 += rl(rlast, k + 3) * W_src[(k + 3) * 64 + lane];
        }
        g = (b0 + b1) + (b2 + b3);
    }
    float v2;
    {
        float b0 = 0.f, b1 = 0.f, b2 = 0.f, b3 = 0.f;
#pragma unroll
        for (int j = 0; j < 32; j += 2) {
            unsigned int u0 = ws32[lane * 33 + j];
            unsigned int u1 = ws32[lane * 33 + j + 1];
            b0 += lof(u0) * rl(g, 2 * j + 0);
            b1 += hif(u0) * rl(g, 2 * j + 1);
            b2 += lof(u1) * rl(g, 2 * j + 2);
            b3 += hif(u1) * rl(g, 2 * j + 3);
        }
        v2 = (b0 + b1) + (b2 + b3);
    }
    float teh;
    {
        float b0 = 0.f, b1 = 0.f, b2 = 0.f, b3 = 0.f;
#pragma unroll
        for (int j = 0; j < 32; j += 2) {
            unsigned int u0 = te32[rr * 33 + j];
            unsigned int u1 = te32[rr * 33 + j + 1];
            b0 += lof(u0) * rl(dh, 2 * j + 0);
            b1 += hif(u0) * rl(dh, 2 * j + 1);
            b2 += lof(u1) * rl(dh, 2 * j + 2);
            b3 += hif(u1) * rl(dh, 2 * j + 3);
        }
        teh = (b0 + b1) + (b2 + b3);
    }
    float e, e1;
    {
        float ea = 0.f, eb = 0.f, qa = 0.f, qb = 0.f;
#pragma unroll
        for (int j = 0; j < 32; j += 2) {
            unsigned int u0 = mbw[rr * 33 + j];
            unsigned int u1 = mbw[rr * 33 + j + 1];
            float m0 = lof(u0), m1 = hif(u0), m2f = lof(u1), m3 = hif(u1);
            ea += m0 * rl(v1, 2 * j + 0) + m1 * rl(v1, 2 * j + 1);
            eb += m2f * rl(v1, 2 * j + 2) + m3 * rl(v1, 2 * j + 3);
            qa += m0 * rl(v2, 2 * j + 0) + m1 * rl(v2, 2 * j + 1);
            qb += m2f * rl(v2, 2 * j + 2) + m3 * rl(v2, 2 * j + 3);
        }
        e = ea + eb; e1 = qa + qb;
    }
    e = (e + __shfl(teh, re_o)) * 0.125f;
    e1 *= 0.125f;
    if (lane >= L) { e = -3e38f; e1 = -3e38f; }
    float mx = e;
#pragma unroll
    for (int s = 32; s; s >>= 1) { float o2 = __shfl_xor(mx, s); mx = (o2 > mx) ? o2 : mx; }
    float ex = __expf(e - mx);
    float sm = ex;
#pragma unroll
    for (int s = 32; s; s >>= 1) sm += __shfl_xor(sm, s);
    float alpha = ex / sm;
    float mx1 = e1;
#pragma unroll
    for (int s = 32; s; s >>= 1) { float o2 = __shfl_xor(mx1, s); mx1 = (o2 > mx1) ? o2 : mx1; }
    float ex1 = __expf(e1 - mx1);
    float sm1 = ex1;
#pragma unroll
    for (int s = 32; s; s >>= 1) sm1 += __shfl_xor(sm1, s);
    float aw = ex1 / sm1;
    float sl, ss, tacc;
    {
        float sA = 0.f, sB = 0.f, hA = 0.f, hB = 0.f, tA = 0.f, tB = 0.f;
        int hcol = lane >> 1, odd = lane & 1;
#pragma unroll
        for (int l = 0; l < L; l += 2) {
            float saA = rl(alpha, l),     s1A = rl(aw, l);
            float saB = rl(alpha, l + 1), s1B = rl(aw, l + 1);
            int   roA = rli(re_o, l),     roB = rli(re_o, l + 1);
            unsigned int uA = mbw[(l + 0) * 33 + hcol];
            unsigned int uB = mbw[(l + 1) * 33 + hcol];
            float mA = odd ? hif(uA) : lof(uA);
            float mB = odd ? hif(uB) : lof(uB);
            sA += saA * mA; hA += s1A * mA; tA += saA * tek[roA * 64 + lane];
            sB += saB * mB; hB += s1B * mB; tB += saB * tek[roB * 64 + lane];
        }
        sl = sA + sB; ss = hA + hB; tacc = tA + tB;
    }
    float hl, hs;
    {
        float lA = 0.f, lB = 0.f, sA = 0.f, sB = 0.f;
#pragma unroll
        for (int k = 0; k < 64; k += 2) {
            float w0 = W_src[(k + 0) * 64 + lane];
            float w1 = W_src[(k + 1) * 64 + lane];
            lA += rl(sl, k + 0) * w0; sA += rl(ss, k + 0) * w0;
            lB += rl(sl, k + 1) * w1; sB += rl(ss, k + 1) * w1;
        }
        hl = tacc + lA + lB; hs = sA + sB;
    }
    float o;
    {
        float o0 = 0.f, o1 = 0.f, o2 = 0.f, o3 = 0.f;
#pragma unroll
        for (int k = 0; k < 64; k += 2) {
            o0 += rl(hl, k + 0) * Wg[(k + 0) * 64 + lane];
            o1 += rl(hl, k + 1) * Wg[(k + 1) * 64 + lane];
            o2 += rl(hs, k + 0) * Wg[(k + 64) * 64 + lane];
            o3 += rl(hs, k + 1) * Wg[(k + 65) * 64 + lane];
        }
        o = f + (o0 + o1) + (o2 + o3);
    }
    o = (o > 0.f) ? o : (__expf(o) - 1.f);
    out[(size_t)n * D + lane] = o;
}

extern "C" void kernel_launch(void* const* d_in, const int* in_sizes, int n_in,
                              void* d_out, int out_size, void* d_ws, size_t ws_size,
                              hipStream_t stream) {
    const float* user_feat = (const float*)d_in[0];
    const float* item_feat = (const float*)d_in[1];
    const float* W_u  = (const float*)d_in[2];
    const float* W_i  = (const float*)d_in[3];
    const float* Wg_u = (const float*)d_in[4];
    const float* Wg_i = (const float*)d_in[5];
    const float* i_te   = (const float*)d_in[6];
    const float* i_te_k = (const float*)d_in[7];
    const float* u_te   = (const float*)d_in[8];
    const float* u_te_k = (const float*)d_in[9];
    const int* item_nbr  = (const int*)d_in[10];
    const int* item_time = (const int*)d_in[11];
    const int* user_nbr  = (const int*)d_in[12];
    const int* user_time = (const int*)d_in[13];
    (void)in_sizes; (void)n_in; (void)out_size;

    float* outp = (float*)d_out;
    const size_t H_BYTES = (size_t)(NUM_U + NUM_I) * 32 * 4;            // 6.4 MB
    const size_t NEED = H_BYTES + 2 * 16384 + 4 * 8192;                 // +64 KB aux

    if (ws_size >= NEED) {
        unsigned int* Hp = (unsigned int*)d_ws;
        unsigned char* aux = (unsigned char*)d_ws + H_BYTES;
        unsigned short* WgPi = (unsigned short*)(aux);
        unsigned short* WgPu = (unsigned short*)(aux + 16384);
        unsigned short* tePi = (unsigned short*)(aux + 32768);
        unsigned short* tePu = (unsigned short*)(aux + 40960);
        unsigned short* tkPi = (unsigned short*)(aux + 49152);
        unsigned short* tkPu = (unsigned short*)(aux + 57344);

        prep<<<GEMM_BLKS + 16, 256, 0, stream>>>(user_feat, item_feat, W_u, W_i,
                                       Wg_i, Wg_u, i_te, u_te, i_te_k, u_te_k,
                                       Hp, WgPi, WgPu, tePi, tePu, tkPi, tkPu);
        attn_fused<<<(NUM_I + NUM_U) / 4, 256, 0, stream>>>(
            Hp, user_feat, item_feat, WgPi, WgPu, tePi, tePu, tkPi, tkPu,
            item_nbr, item_time, user_nbr, user_time, outp);
    } else {
        attn_mono<<<NUM_I / 4, 256, 0, stream>>>(
            user_feat, item_feat, W_u, W_i, Wg_i, i_te, i_te_k,
            item_nbr, item_time, outp + (size_t)NUM_U * D);
        attn_mono<<<NUM_U / 4, 256, 0, stream>>>(
            item_feat, user_feat, W_i, W_u, Wg_u, u_te, u_te_k,
            user_nbr, user_time, outp);
    }
}

// Round 8
// 229.636 us; speedup vs baseline: 1.1001x; 1.0090x over previous
//
#include <hip/hip_runtime.h>
#include <stdint.h>

#define D   64
#define L   50
#define NUM_U 30000
#define NUM_I 20000
#define MROWS 50
#define REG_OFF 1600                  // region base (dw): mailbox is 1600 dw
#define PW3 1696                      // 1600 mailbox + 96-dw u16 region = 27136 B/block
#define GEMM_BLKS 782                 // 3125 row-tiles of 16, 4 waves/block

// r9: 241.5 (attn 144). r10: global gathers REGRESSED. r11: DMA fill +
//     chunk-XOR swizzle: attn 137.7. r12: prep->MFMA; residue = harness.
// r13: reg-prefetch REGRESSED (scratch spill); swizzle VALIDATED (7.7M->0.9M).
// r14: FAILED: float<->u16 LDS overlay -> TBAA reorder. u16-only overlays OK.
// r15: shfl extraction, LDS 27136: passed, 144us, occupancy STILL 53%.
//     LDS diets (r12,r15) never moved occupancy -> limiter is the UNIFIED
//     register file: 40-48 VGPR + 64 AGPR (16 live f32x4 accs) ~= 104-112
//     -> 4 waves/SIMD = 50% == measured. rocprof VGPR_Count excludes AGPRs.
// r16: accumulator diet 64->16: nt-outer/kt-inner, acc pair scoped per tile,
//     extraction at tile end. FP order per acc unchanged (kt0 then kt1).
//     Budget ~60-70 regs -> launch_bounds(256,6) honorable; LDS caps 6
//     blocks/CU = 75%. Test: occupancy must rise; WRITE_SIZE is spill guard.
// r17: r16 resubmitted verbatim (round-7 bench was a broker/container
//     failure, no kernel signal).

typedef __attribute__((ext_vector_type(8))) short short8x;   // 8 bf16
typedef __attribute__((ext_vector_type(4))) float f32x4;     // MFMA acc

__device__ __forceinline__ float lof(unsigned int u) {
    union { unsigned int i; float f; } v; v.i = u << 16; return v.f;
}
__device__ __forceinline__ float hif(unsigned int u) {
    union { unsigned int i; float f; } v; v.i = u & 0xffff0000u; return v.f;
}
__device__ __forceinline__ unsigned int f2bfbits(float f) {
    union { float f; unsigned int i; } v; v.f = f;
    return (v.i + 0x7fffu + ((v.i >> 16) & 1u)) >> 16;   // RNE
}
__device__ __forceinline__ unsigned int packbf(float a, float b) {
    return f2bfbits(a) | (f2bfbits(b) << 16);
}
__device__ __forceinline__ float rl(float v, int l) {
    return __int_as_float(__builtin_amdgcn_readlane(__float_as_int(v), l));
}
__device__ __forceinline__ int rli(int v, int l) {
    return __builtin_amdgcn_readlane(v, l);
}
__device__ __forceinline__ void gload_lds16(const void* g, void* l) {
    __builtin_amdgcn_global_load_lds(
        (const __attribute__((address_space(1))) unsigned int*)g,
        (__attribute__((address_space(3))) unsigned int*)l, 16, 0, 0);
}
// select v[idx] for 2-bit idx via cndmask tree
__device__ __forceinline__ float sel4(float v0, float v1, float v2, float v3, int idx) {
    float a = (idx & 1) ? v1 : v0;
    float b = (idx & 1) ? v3 : v2;
    return (idx & 2) ? b : a;
}

// ---------------- K1: fused prep: H = feat@W (MFMA) + bf16 weight packing ---
__global__ __launch_bounds__(256) void prep(
    const float* __restrict__ user_feat, const float* __restrict__ item_feat,
    const float* __restrict__ W_u, const float* __restrict__ W_i,
    const float* __restrict__ Wg_i, const float* __restrict__ Wg_u,
    const float* __restrict__ te_i, const float* __restrict__ te_u,
    const float* __restrict__ tk_i, const float* __restrict__ tk_u,
    unsigned int* __restrict__ H,
    unsigned short* __restrict__ WgPi, unsigned short* __restrict__ WgPu,
    unsigned short* __restrict__ tePi, unsigned short* __restrict__ tePu,
    unsigned short* __restrict__ tkPi, unsigned short* __restrict__ tkPu)
{
    const int tid = threadIdx.x;
    if (blockIdx.x < GEMM_BLKS) {
        const int lane = tid & 63, wid = tid >> 6;
        const int tile = blockIdx.x * 4 + wid;            // 16 rows per tile
        if (tile >= 3125) return;                         // 3125*16 = 50000 exact
        const int r0 = tile * 16;
        const float* src; const float* W;
        if (r0 < NUM_U) { src = user_feat + (size_t)r0 * D;            W = W_u; }
        else            { src = item_feat + (size_t)(r0 - NUM_U) * D;  W = W_i; }
        const int q4 = lane >> 4, c16 = lane & 15;

        // B-frags: feat rows. B[n=c16][k=kt*32+q4*8+j], coalesced float4 pairs.
        short8x bf[2];
#pragma unroll
        for (int kt = 0; kt < 2; kt++) {
            const float* fp = src + c16 * D + kt * 32 + q4 * 8;
            float4 x = *(const float4*)fp;
            float4 y = *(const float4*)(fp + 4);
            union { short8x v; unsigned int u[4]; } t2;
            t2.u[0] = packbf(x.x, x.y); t2.u[1] = packbf(x.z, x.w);
            t2.u[2] = packbf(y.x, y.y); t2.u[3] = packbf(y.z, y.w);
            bf[kt] = t2.v;
        }
        // A-frags: W^T. A[m=c16+16mt][k] = W[k][c16+16mt]; W is 16KB, L1-hot.
        f32x4 zero4 = {0.f, 0.f, 0.f, 0.f};
        f32x4 acc[4];
#pragma unroll
        for (int mt = 0; mt < 4; mt++) acc[mt] = zero4;
#pragma unroll
        for (int kt = 0; kt < 2; kt++) {
#pragma unroll
            for (int mt = 0; mt < 4; mt++) {
                union { short8x v; unsigned short u[8]; } a;
#pragma unroll
                for (int j = 0; j < 8; j++)
                    a.u[j] = (unsigned short)f2bfbits(
                        W[(kt * 32 + q4 * 8 + j) * D + c16 + 16 * mt]);
                acc[mt] = __builtin_amdgcn_mfma_f32_16x16x32_bf16(a.v, bf[kt], acc[mt], 0, 0, 0);
            }
        }
        // D[m][n]: col(c16) = feat row n, reg row = m = q4*4+r -> H col.
        unsigned int* Hrow = H + (size_t)(r0 + c16) * 32;
#pragma unroll
        for (int mt = 0; mt < 4; mt++) {
            uint2 pk;
            pk.x = packbf(acc[mt][0], acc[mt][1]);
            pk.y = packbf(acc[mt][2], acc[mt][3]);
            *(uint2*)(Hrow + 8 * mt + 2 * q4) = pk;
        }
    } else {
        int gid = (blockIdx.x - GEMM_BLKS) * 256 + tid;   // 16 blocks, gs=4096
        for (int idx = gid; idx < 8192; idx += 4096) {
            int n = idx >> 7, k = idx & 127;
            WgPi[idx] = (unsigned short)f2bfbits(Wg_i[k * 64 + n]);
            WgPu[idx] = (unsigned short)f2bfbits(Wg_u[k * 64 + n]);
        }
        {
            int idx = gid;                                // 4096 elements, 1 iter
            int r = idx >> 6, k = idx & 63;
            tePi[idx] = (r < L) ? (unsigned short)f2bfbits(te_i[r * 64 + k]) : 0;
            tePu[idx] = (r < L) ? (unsigned short)f2bfbits(te_u[r * 64 + k]) : 0;
            int d = idx >> 6, rr = idx & 63;
            tkPi[idx] = (rr < L) ? (unsigned short)f2bfbits(tk_i[rr * 64 + d]) : 0;
            tkPu[idx] = (rr < L) ? (unsigned short)f2bfbits(tk_u[rr * 64 + d]) : 0;
        }
    }
}

// ---------------- K2: fused attention, both sides, MFMA math ----------------
// Swizzle: LDS[row][pc] = G[row][pc ^ swz(row)], swz(row) = (row&7) ^
// (((row>>3)&3)<<1). Sums gather conflict-free; scores b128 <=2-way.
// u16-only 96-dw region: {dh|lm} -> {alpha|a1|beta} -> {cat}.
// Accumulators scoped per output tile: peak 2 f32x4 pairs (16 regs).
__global__ __launch_bounds__(256, 6) void attn_fused(
    const unsigned int* __restrict__ H,
    const float* __restrict__ user_feat, const float* __restrict__ item_feat,
    const unsigned short* __restrict__ WgPi, const unsigned short* __restrict__ WgPu,
    const unsigned short* __restrict__ tePi, const unsigned short* __restrict__ tePu,
    const unsigned short* __restrict__ tkPi, const unsigned short* __restrict__ tkPu,
    const int* __restrict__ item_nbr, const int* __restrict__ item_time,
    const int* __restrict__ user_nbr, const int* __restrict__ user_time,
    float* __restrict__ out)
{
    __shared__ unsigned int lds[4 * PW3];   // 27136 B -> 6 blocks/CU

    const int tid = threadIdx.x, lane = tid & 63, wid = tid >> 6;
    const bool iside = blockIdx.x < (NUM_I / 4);
    const int bb = iside ? blockIdx.x : blockIdx.x - NUM_I / 4;
    const int n = bb * 4 + wid;
    const int src_base = iside ? 0 : NUM_U;
    const int dst_base = iside ? NUM_U : 0;
    const float* dst_feat = iside ? item_feat : user_feat;
    const unsigned short* WgP  = iside ? WgPi : WgPu;
    const unsigned short* teP  = iside ? tePi : tePu;
    const unsigned short* tekP = iside ? tkPi : tkPu;
    const int* nbr   = iside ? item_nbr  : user_nbr;
    const int* timev = iside ? item_time : user_time;
    float* outp = out + (iside ? (size_t)NUM_U * D : 0);

    const int q4 = lane >> 4, c16 = lane & 15;

    const unsigned int*   Hsrc = H + (size_t)src_base * 32;
    const unsigned short* Hs16 = (const unsigned short*)H + (size_t)src_base * 64;
    const unsigned short* Hd16 = (const unsigned short*)H + (size_t)dst_base * 64;

    // per-wave LDS slices
    unsigned int*   wld = lds + wid * PW3;
    unsigned int*   mbw = wld;                             // 50 rows x 32 dw, swizzled
    unsigned short* dla = (unsigned short*)(wld + REG_OFF);    // u16-only region
    unsigned short* cat = (unsigned short*)(wld + REG_OFF);    // overlay (u16, same type)

    // ---- metadata ----
    int t   = (lane < L) ? timev[(size_t)n * L + lane] : 0;
    int nbv = (lane < L) ? nbr[(size_t)n * L + lane]  : 0;

    // ---- mailbox fill: rows 0..47 via global_load_lds (16B/lane, 8 rows/instr)
    {
        const int soff = (((lane & 7) ^ (lane >> 3)) << 4);   // g-invariant part
        const int rsel = (lane >> 3) << 2;                    // bpermute byte idx
#pragma unroll
        for (int g = 0; g < 6; g++) {
            int nb = __builtin_amdgcn_ds_bpermute(rsel + (g << 5), nbv);
            const char* gp = (const char*)(Hsrc + (size_t)(unsigned)nb * 32)
                             + (soff ^ ((g & 3) << 5));
            gload_lds16(gp, (char*)mbw + (g << 10));
        }
        // rows 48..49: one manual pass (2 rows x 32 dw over 64 lanes)
        int row = 48 + (lane >> 5), d = lane & 31;
        int nb = __builtin_amdgcn_ds_bpermute(row << 2, nbv);
        unsigned int v = Hsrc[(size_t)(unsigned)nb * 32 + d];
        int swzr = (row & 7) ^ (((row >> 3) & 3) << 1);
        mbw[(row << 5) + ((((d >> 2) ^ swzr) << 2) | (d & 3))] = v;
    }

    // ---- last (before rank so dh/lm loads issue early, short liveness) ----
    unsigned int key2 = (lane < L) ? ((((unsigned)t) << 6) | (unsigned)(63 - lane)) : 0u;
    unsigned int m2 = key2;
#pragma unroll
    for (int s = 32; s; s >>= 1) { unsigned int o2 = __shfl_xor(m2, s); m2 = (o2 > m2) ? o2 : m2; }
    const int last = 63 - (int)(m2 & 63u);
    int nbl = __shfl(nbv, last);                      // last is wave-uniform
    unsigned short dh_u = Hd16[(size_t)n * 64 + lane];              // 2 u16 loads,
    unsigned short lm_u = Hs16[(size_t)(unsigned)nbl * 64 + lane];  // hide under rank

    // ---- rank ----
    unsigned int key = (lane < L) ? ((((unsigned)t) << 6) | (unsigned)lane) : 0u;
    int rank = 0;
#pragma unroll
    for (int j = 0; j < L; j++) {
        unsigned int kj = (unsigned int)rli((int)key, j);
        rank += (kj < key) ? 1 : 0;
    }
    int re_o = (lane < L) ? (L - 1 - rank) : lane;   // pad lanes: distinct slots

    // ---- region phase 0: dh|lm (raw bf16, bit-identical) ----
    dla[lane]      = dh_u;
    dla[64 + lane] = lm_u;

    f32x4 zero4 = {0.f, 0.f, 0.f, 0.f};
    // A-frags (kt=0,1), read once; dead after scores phase
    short8x afr0 = *(const short8x*)(dla + (c16 & 1) * 64 + 0 * 32 + q4 * 8);
    short8x afr1 = *(const short8x*)(dla + (c16 & 1) * 64 + 1 * 32 + q4 * 8);

    // ---- scores + teh via MFMA, one output tile at a time (acc diet) ----
    // slot j of e/e1/teh lives on lane j&15, register [0]/[1], tile nt=j>>4.
    const int rsrc = re_o & 15;
    float eX0, eX1, eX2, eX3, gX0, gX1, gX2, gX3, tX0, tX1, tX2, tX3;
    __builtin_amdgcn_s_setprio(1);
#define SCORE_TILE(NT, EO, GO, TO)                                             \
    {                                                                          \
        f32x4 aE = zero4, aT = zero4;                                          \
        const int row = c16 + 16 * NT;                                         \
        const int rowc = (row < MROWS) ? row : 0;   /* rows>=50 masked later */\
        const int swzr = (rowc & 7) ^ (((rowc >> 3) & 3) << 1);                \
        short8x bv0 = *(const short8x*)((const char*)mbw + rowc * 128          \
                                        + ((q4 ^ swzr) << 4));                 \
        short8x bt0 = *(const short8x*)(teP + row * 64 + q4 * 8);              \
        aE = __builtin_amdgcn_mfma_f32_16x16x32_bf16(afr0, bv0, aE, 0, 0, 0);  \
        aT = __builtin_amdgcn_mfma_f32_16x16x32_bf16(afr0, bt0, aT, 0, 0, 0);  \
        short8x bv1 = *(const short8x*)((const char*)mbw + rowc * 128          \
                                        + (((4 + q4) ^ swzr) << 4));           \
        short8x bt1 = *(const short8x*)(teP + row * 64 + 32 + q4 * 8);         \
        aE = __builtin_amdgcn_mfma_f32_16x16x32_bf16(afr1, bv1, aE, 0, 0, 0);  \
        aT = __builtin_amdgcn_mfma_f32_16x16x32_bf16(afr1, bt1, aT, 0, 0, 0);  \
        EO = __shfl(aE[0], c16);                                               \
        GO = __shfl(aE[1], c16);                                               \
        TO = __shfl(aT[0], rsrc);                                              \
    }
    SCORE_TILE(0, eX0, gX0, tX0)
    SCORE_TILE(1, eX1, gX1, tX1)
    SCORE_TILE(2, eX2, gX2, tX2)
    SCORE_TILE(3, eX3, gX3, tX3)
#undef SCORE_TILE
    __builtin_amdgcn_s_setprio(0);

    float e  = sel4(eX0, eX1, eX2, eX3, q4);
    float e1 = sel4(gX0, gX1, gX2, gX3, q4);
    float th = sel4(tX0, tX1, tX2, tX3, (re_o >> 4) & 3);

    e = (e + th) * 0.125f;
    e1 *= 0.125f;
    if (lane >= L) { e = -3e38f; e1 = -3e38f; }

    // ---- dual softmax over neighbors ----
    float mx = e;
#pragma unroll
    for (int s = 32; s; s >>= 1) { float o2 = __shfl_xor(mx, s); mx = (o2 > mx) ? o2 : mx; }
    float ex = __expf(e - mx);
    float sm = ex;
#pragma unroll
    for (int s = 32; s; s >>= 1) sm += __shfl_xor(sm, s);
    float alpha = ex / sm;

    float mx1 = e1;
#pragma unroll
    for (int s = 32; s; s >>= 1) { float o2 = __shfl_xor(mx1, s); mx1 = (o2 > mx1) ? o2 : mx1; }
    float ex1 = __expf(e1 - mx1);
    float sm1 = ex1;
#pragma unroll
    for (int s = 32; s; s >>= 1) sm1 += __shfl_xor(sm1, s);
    float aw = ex1 / sm1;

    // ---- region phase 1: alpha|a1|beta (bf16, u16-only overlay) ----
    // pad lanes: alpha == aw == 0 exactly -> rows >=50 contribute nothing below
    dla[lane]       = (unsigned short)f2bfbits(alpha);
    dla[64 + lane]  = (unsigned short)f2bfbits(aw);
    dla[128 + re_o] = (unsigned short)f2bfbits(alpha);   // beta[r]: alpha at rank r

    // ---- sums via MFMA, one output tile at a time (acc diet) ----
    short8x aS0 = *(const short8x*)(dla + (c16 & 1) * 64 + 0 * 32 + q4 * 8);
    short8x aS1 = *(const short8x*)(dla + (c16 & 1) * 64 + 1 * 32 + q4 * 8);
    short8x aB0 = *(const short8x*)(dla + 128 + 0 * 32 + q4 * 8);
    short8x aB1 = *(const short8x*)(dla + 128 + 1 * 32 + q4 * 8);
    const int qx = q4 << 1;                           // swizzle high bits
    __builtin_amdgcn_s_setprio(1);
#define SUM_TILE(NT)                                                           \
    {                                                                          \
        f32x4 aS = zero4, aK = zero4;                                          \
        const int dc = c16 + 16 * NT;                                          \
        const int tq = (dc >> 3) ^ qx;                                         \
        const char* cbase = (const char*)mbw + ((dc & 7) << 1);                \
        union { short8x v; unsigned short u[8]; } bu;                          \
        _Pragma("unroll")                                                      \
        for (int i = 0; i < 8; i++) {                                          \
            int k = q4 * 8 + i;              /* kt=0: k&7==i, (k>>3)&3==q4 */  \
            bu.u[i] = *(const unsigned short*)(cbase + (k << 7) + ((tq ^ i) << 4)); \
        }                                                                      \
        short8x bK0 = *(const short8x*)(tekP + dc * 64 + q4 * 8);              \
        aS = __builtin_amdgcn_mfma_f32_16x16x32_bf16(aS0, bu.v, aS, 0, 0, 0);  \
        aK = __builtin_amdgcn_mfma_f32_16x16x32_bf16(aB0, bK0, aK, 0, 0, 0);   \
        _Pragma("unroll")                                                      \
        for (int i = 0; i < 8; i++) {                                          \
            int k = 32 + q4 * 8 + i;                                           \
            k = (k < MROWS) ? k : (k - 32);  /* alpha=0 rows: any finite row */\
            bu.u[i] = *(const unsigned short*)(cbase + (k << 7) + ((tq ^ i) << 4)); \
        }                                                                      \
        short8x bK1 = *(const short8x*)(tekP + dc * 64 + 32 + q4 * 8);         \
        aS = __builtin_amdgcn_mfma_f32_16x16x32_bf16(aS1, bu.v, aS, 0, 0, 0);  \
        aK = __builtin_amdgcn_mfma_f32_16x16x32_bf16(aB1, bK1, aK, 0, 0, 0);   \
        if (q4 == 0) {                                                         \
            cat[c16 + 16 * NT]      = (unsigned short)f2bfbits(aS[0] + aK[0]); \
            cat[64 + c16 + 16 * NT] = (unsigned short)f2bfbits(aS[1]);         \
        }                                                                      \
    }
    SUM_TILE(0)
    SUM_TILE(1)
    SUM_TILE(2)
    SUM_TILE(3)
#undef SUM_TILE
    __builtin_amdgcn_s_setprio(0);
    __syncthreads();   // only barrier: epilogue mixes waves' cat rows

    // ---- epilogue: out = elu(cat @ Wg + f) ----
    short8x bfr[4];
#pragma unroll
    for (int tK = 0; tK < 4; tK++)
        bfr[tK] = *(const short8x*)(WgP + (wid * 16 + c16) * 128 + tK * 32 + q4 * 8);

    const unsigned short* catw =
        (const unsigned short*)(lds + (lane & 3) * PW3 + REG_OFF);
    f32x4 acc = zero4;
#pragma unroll
    for (int tK = 0; tK < 4; tK++) {
        short8x a = *(const short8x*)(catw + tK * 32 + q4 * 8);
        acc = __builtin_amdgcn_mfma_f32_16x16x32_bf16(a, bfr[tK], acc, 0, 0, 0);
    }
    float r01 = (q4 & 1) ? acc[1] : acc[0];
    float r23 = (q4 & 1) ? acc[3] : acc[2];
    float pv  = (q4 & 2) ? r23 : r01;

    int node = bb * 4 + q4;
    float fres = dst_feat[(size_t)node * D + wid * 16 + c16];
    float oo = pv + fres;
    oo = (oo > 0.f) ? oo : (__expf(oo) - 1.f);
    outp[(size_t)node * D + wid * 16 + c16] = oo;
}

// ---------------- fallback: round-5 monolith (passed, 447us) ---------------
__global__ __launch_bounds__(256) void attn_mono(
    const float* __restrict__ src_feat, const float* __restrict__ dst_feat,
    const float* __restrict__ W_src, const float* __restrict__ W_dst,
    const float* __restrict__ Wg, const float* __restrict__ te,
    const float* __restrict__ tek, const int* __restrict__ nbr,
    const int* __restrict__ timev, float* __restrict__ out)
{
    __shared__ unsigned int ws32[64 * 33];
    __shared__ unsigned int te32[L * 33];
    __shared__ unsigned int mbs[4][L * 33];
    const int tid = threadIdx.x, lane = tid & 63, wid = tid >> 6;
    const int n = blockIdx.x * 4 + wid;
    {
        const float2* Wf2 = (const float2*)W_src;
        const float2* Te2 = (const float2*)te;
        for (int idx = tid; idx < 2048; idx += 256) {
            float2 w = Wf2[idx];
            ws32[(idx >> 5) * 33 + (idx & 31)] = packbf(w.x, w.y);
            if (idx < 1600) {
                float2 t2 = Te2[idx];
                te32[(idx >> 5) * 33 + (idx & 31)] = packbf(t2.x, t2.y);
            }
        }
    }
    __syncthreads();
    int t  = (lane < L) ? timev[(size_t)n * L + lane] : 0;
    int nb = (lane < L) ? nbr[(size_t)n * L + lane]  : 0;
    unsigned int key  = (lane < L) ? ((((unsigned)t) << 6) | (unsigned)lane) : 0u;
    unsigned int key2 = (lane < L) ? ((((unsigned)t) << 6) | (unsigned)(63 - lane)) : 0u;
    int rank = 0;
#pragma unroll
    for (int j = 0; j < L; j++) {
        unsigned int kj = (unsigned int)rli((int)key, j);
        rank += (kj < key) ? 1 : 0;
    }
    int re_o = (lane < L) ? (L - 1 - rank) : 0;
    unsigned int m2 = key2;
#pragma unroll
    for (int s = 32; s; s >>= 1) { unsigned int o2 = __shfl_xor(m2, s); m2 = (o2 > m2) ? o2 : m2; }
    const int last = 63 - (int)(m2 & 63u);
    const int rr = (lane < L) ? lane : (L - 1);
    float f = dst_feat[(size_t)n * D + lane];
    float dh;
    {
        float b0 = 0.f, b1 = 0.f, b2 = 0.f, b3 = 0.f;
#pragma unroll
        for (int k = 0; k < 64; k += 4) {
            b0 += rl(f, k + 0) * W_dst[(k + 0) * 64 + lane];
            b1 += rl(f, k + 1) * W_dst[(k + 1) * 64 + lane];
            b2 += rl(f, k + 2) * W_dst[(k + 2) * 64 + lane];
            b3 += rl(f, k + 3) * W_dst[(k + 3) * 64 + lane];
        }
        dh = (b0 + b1) + (b2 + b3);
    }
    float v1;
    {
        float b0 = 0.f, b1 = 0.f, b2 = 0.f, b3 = 0.f;
#pragma unroll
        for (int j = 0; j < 32; j += 2) {
            unsigned int u0 = ws32[lane * 33 + j];
            unsigned int u1 = ws32[lane * 33 + j + 1];
            b0 += lof(u0) * rl(dh, 2 * j + 0);
            b1 += hif(u0) * rl(dh, 2 * j + 1);
            b2 += lof(u1) * rl(dh, 2 * j + 2);
            b3 += hif(u1) * rl(dh, 2 * j + 3);
        }
        v1 = (b0 + b1) + (b2 + b3);
    }
    unsigned int* mbw = mbs[wid];
    {
        const float2* src2 = (const float2*)src_feat;
        int half = lane >> 5, col = lane & 31;
#pragma unroll
        for (int l = 0; l < L; l += 2) {
            int ra = rli(nb, l), rb = rli(nb, l + 1);
            int r = half ? rb : ra;
            float2 v = src2[(size_t)r * 32 + col];
            mbw[(l + half) * 33 + col] = packbf(v.x, v.y);
        }
    }
    __syncthreads();
    unsigned int ul = mbw[last * 33 + (lane >> 1)];
    float rlast = (lane & 1) ? hif(ul) : lof(ul);
    float g;
    {
        float b0 = 0.f, b1 = 0.f, b2 = 0.f, b3 = 0.f;
#pragma unroll
        for (int k = 0; k < 64; k += 4) {
            b0 += rl(rlast, k + 0) * W_src[(k + 0) * 64 + lane];
            b1 += rl(rlast, k + 1) * W_src[(k + 1) * 64 + lane];
            b2 += rl(rlast, k + 2) * W_src[(k + 2) * 64 + lane];
            b3 += rl(rlast, k + 3) * W_src[(k + 3) * 64 + lane];
        }
        g = (b0 + b1) + (b2 + b3);
    }
    float v2;
    {
        float b0 = 0.f, b1 = 0.f, b2 = 0.f, b3 = 0.f;
#pragma unroll
        for (int j = 0; j < 32; j += 2) {
            unsigned int u0 = ws32[lane * 33 + j];
            unsigned int u1 = ws32[lane * 33 + j + 1];
            b0 += lof(u0) * rl(g, 2 * j + 0);
            b1 += hif(u0) * rl(g, 2 * j + 1);
            b2 += lof(u1) * rl(g, 2 * j + 2);
            b3 += hif(u1) * rl(g, 2 * j + 3);
        }
        v2 = (b0 + b1) + (b2 + b3);
    }
    float teh;
    {
        float b0 = 0.f, b1 = 0.f, b2 = 0.f, b3 = 0.f;
#pragma unroll
        for (int j = 0; j < 32; j += 2) {
            unsigned int u0 = te32[rr * 33 + j];
            unsigned int u1 = te32[rr * 33 + j + 1];
            b0 += lof(u0) * rl(dh, 2 * j + 0);
            b1 += hif(u0) * rl(dh, 2 * j + 1);
            b2 += lof(u1) * rl(dh, 2 * j + 2);
            b3 += hif(u1) * rl(dh, 2 * j + 3);
        }
        teh = (b0 + b1) + (b2 + b3);
    }
    float e, e1;
    {
        float ea = 0.f, eb = 0.f, qa = 0.f, qb = 0.f;
#pragma unroll
        for (int j = 0; j < 32; j += 2) {
            unsigned int u0 = mbw[rr * 33 + j];
            unsigned int u1 = mbw[rr * 33 + j + 1];
            float m0 = lof(u0), m1 = hif(u0), m2f = lof(u1), m3 = hif(u1);
            ea += m0 * rl(v1, 2 * j + 0) + m1 * rl(v1, 2 * j + 1);
            eb += m2f * rl(v1, 2 * j + 2) + m3 * rl(v1, 2 * j + 3);
            qa += m0 * rl(v2, 2 * j + 0) + m1 * rl(v2, 2 * j + 1);
            qb += m2f * rl(v2, 2 * j + 2) + m3 * rl(v2, 2 * j + 3);
        }
        e = ea + eb; e1 = qa + qb;
    }
    e = (e + __shfl(teh, re_o)) * 0.125f;
    e1 *= 0.125f;
    if (lane >= L) { e = -3e38f; e1 = -3e38f; }
    float mx = e;
#pragma unroll
    for (int s = 32; s; s >>= 1) { float o2 = __shfl_xor(mx, s); mx = (o2 > mx) ? o2 : mx; }
    float ex = __expf(e - mx);
    float sm = ex;
#pragma unroll
    for (int s = 32; s; s >>= 1) sm += __shfl_xor(sm, s);
    float alpha = ex / sm;
    float mx1 = e1;
#pragma unroll
    for (int s = 32; s; s >>= 1) { float o2 = __shfl_xor(mx1, s); mx1 = (o2 > mx1) ? o2 : mx1; }
    float ex1 = __expf(e1 - mx1);
    float sm1 = ex1;
#pragma unroll
    for (int s = 32; s; s >>= 1) sm1 += __shfl_xor(sm1, s);
    float aw = ex1 / sm1;
    float sl, ss, tacc;
    {
        float sA = 0.f, sB = 0.f, hA = 0.f, hB = 0.f, tA = 0.f, tB = 0.f;
        int hcol = lane >> 1, odd = lane & 1;
#pragma unroll
        for (int l = 0; l < L; l += 2) {
            float saA = rl(alpha, l),     s1A = rl(aw, l);
            float saB = rl(alpha, l + 1), s1B = rl(aw, l + 1);
            int   roA = rli(re_o, l),     roB = rli(re_o, l + 1);
            unsigned int uA = mbw[(l + 0) * 33 + hcol];
            unsigned int uB = mbw[(l + 1) * 33 + hcol];
            float mA = odd ? hif(uA) : lof(uA);
            float mB = odd ? hif(uB) : lof(uB);
            sA += saA * mA; hA += s1A * mA; tA += saA * tek[roA * 64 + lane];
            sB += saB * mB; hB += s1B * mB; tB += saB * tek[roB * 64 + lane];
        }
        sl = sA + sB; ss = hA + hB; tacc = tA + tB;
    }
    float hl, hs;
    {
        float lA = 0.f, lB = 0.f, sA = 0.f, sB = 0.f;
#pragma unroll
        for (int k = 0; k < 64; k += 2) {
            float w0 = W_src[(k + 0) * 64 + lane];
            float w1 = W_src[(k + 1) * 64 + lane];
            lA += rl(sl, k + 0) * w0; sA += rl(ss, k + 0) * w0;
            lB += rl(sl, k + 1) * w1; sB += rl(ss, k + 1) * w1;
        }
        hl = tacc + lA + lB; hs = sA + sB;
    }
    float o;
    {
        float o0 = 0.f, o1 = 0.f, o2 = 0.f, o3 = 0.f;
#pragma unroll
        for (int k = 0; k < 64; k += 2) {
            o0 += rl(hl, k + 0) * Wg[(k + 0) * 64 + lane];
            o1 += rl(hl, k + 1) * Wg[(k + 1) * 64 + lane];
            o2 += rl(hs, k + 0) * Wg[(k + 64) * 64 + lane];
            o3 += rl(hs, k + 1) * Wg[(k + 65) * 64 + lane];
        }
        o = f + (o0 + o1) + (o2 + o3);
    }
    o = (o > 0.f) ? o : (__expf(o) - 1.f);
    out[(size_t)n * D + lane] = o;
}

extern "C" void kernel_launch(void* const* d_in, const int* in_sizes, int n_in,
                              void* d_out, int out_size, void* d_ws, size_t ws_size,
                              hipStream_t stream) {
    const float* user_feat = (const float*)d_in[0];
    const float* item_feat = (const float*)d_in[1];
    const float* W_u  = (const float*)d_in[2];
    const float* W_i  = (const float*)d_in[3];
    const float* Wg_u = (const float*)d_in[4];
    const float* Wg_i = (const float*)d_in[5];
    const float* i_te   = (const float*)d_in[6];
    const float* i_te_k = (const float*)d_in[7];
    const float* u_te   = (const float*)d_in[8];
    const float* u_te_k = (const float*)d_in[9];
    const int* item_nbr  = (const int*)d_in[10];
    const int* item_time = (const int*)d_in[11];
    const int* user_nbr  = (const int*)d_in[12];
    const int* user_time = (const int*)d_in[13];
    (void)in_sizes; (void)n_in; (void)out_size;

    float* outp = (float*)d_out;
    const size_t H_BYTES = (size_t)(NUM_U + NUM_I) * 32 * 4;            // 6.4 MB
    const size_t NEED = H_BYTES + 2 * 16384 + 4 * 8192;                 // +64 KB aux

    if (ws_size >= NEED) {
        unsigned int* Hp = (unsigned int*)d_ws;
        unsigned char* aux = (unsigned char*)d_ws + H_BYTES;
        unsigned short* WgPi = (unsigned short*)(aux);
        unsigned short* WgPu = (unsigned short*)(aux + 16384);
        unsigned short* tePi = (unsigned short*)(aux + 32768);
        unsigned short* tePu = (unsigned short*)(aux + 40960);
        unsigned short* tkPi = (unsigned short*)(aux + 49152);
        unsigned short* tkPu = (unsigned short*)(aux + 57344);

        prep<<<GEMM_BLKS + 16, 256, 0, stream>>>(user_feat, item_feat, W_u, W_i,
                                       Wg_i, Wg_u, i_te, u_te, i_te_k, u_te_k,
                                       Hp, WgPi, WgPu, tePi, tePu, tkPi, tkPu);
        attn_fused<<<(NUM_I + NUM_U) / 4, 256, 0, stream>>>(
            Hp, user_feat, item_feat, WgPi, WgPu, tePi, tePu, tkPi, tkPu,
            item_nbr, item_time, user_nbr, user_time, outp);
    } else {
        attn_mono<<<NUM_I / 4, 256, 0, stream>>>(
            user_feat, item_feat, W_u, W_i, Wg_i, i_te, i_te_k,
            item_nbr, item_time, outp + (size_t)NUM_U * D);
        attn_mono<<<NUM_U / 4, 256, 0, stream>>>(
            item_feat, user_feat, W_i, W_u, Wg_u, u_te, u_te_k,
            user_nbr, user_time, outp);
    }
}

// Round 9
// 203.665 us; speedup vs baseline: 1.2404x; 1.1275x over previous
//
#include <hip/hip_runtime.h>
#include <stdint.h>

#define D   64
#define L   50
#define NUM_U 30000
#define NUM_I 20000
#define MROWS 50
#define REG_OFF 1600                  // mailbox is 1600 dw
#define PW3 1888                      // mailbox 1600 | dla 96 | escf 192 -> 30208 B/block
#define GEMM_BLKS 782                 // 3125 row-tiles of 16, 4 waves/block

// r9: 241.5 (attn 144). r10: global gathers REGRESSED. r11: DMA fill +
//     chunk-XOR swizzle: attn 137.7 (BEST). r12: prep->MFMA; residue=harness.
// r13: reg-prefetch REGRESSED (spill); EXTENDED swizzle VALIDATED (0.8-0.9M).
// r14: FAILED: float<->u16 LDS overlay TBAA reorder (data-dep ordering is OK).
// r15/r16: LDS diet + acc diet: occupancy PINNED at 53.5% regardless ->
//     occupancy is not movable by LDS/regs; acc diet lost ILP (141 vs 137.7).
// r18: shorten the per-wave chain instead: teh = te @ H_dst is node-only ->
//     precompute in prep (8 MFMA per 16 nodes, bitwise-identical kt order,
//     12.8MB f32 table in ws), attn reads teh[n][re_o] (1 load, hidden under
//     scores). Revert scores/sums to kt-outer ILP (r12), keep ext swizzle,
//     launch_bounds(256,5). ws<19.3MB -> tehT=nullptr -> in-kernel teh path.

typedef __attribute__((ext_vector_type(8))) short short8x;   // 8 bf16
typedef __attribute__((ext_vector_type(4))) float f32x4;     // MFMA acc

__device__ __forceinline__ float lof(unsigned int u) {
    union { unsigned int i; float f; } v; v.i = u << 16; return v.f;
}
__device__ __forceinline__ float hif(unsigned int u) {
    union { unsigned int i; float f; } v; v.i = u & 0xffff0000u; return v.f;
}
__device__ __forceinline__ unsigned int f2bfbits(float f) {
    union { float f; unsigned int i; } v; v.f = f;
    return (v.i + 0x7fffu + ((v.i >> 16) & 1u)) >> 16;   // RNE
}
__device__ __forceinline__ unsigned int packbf(float a, float b) {
    return f2bfbits(a) | (f2bfbits(b) << 16);
}
__device__ __forceinline__ float rl(float v, int l) {
    return __int_as_float(__builtin_amdgcn_readlane(__float_as_int(v), l));
}
__device__ __forceinline__ int rli(int v, int l) {
    return __builtin_amdgcn_readlane(v, l);
}
__device__ __forceinline__ void gload_lds16(const void* g, void* l) {
    __builtin_amdgcn_global_load_lds(
        (const __attribute__((address_space(1))) unsigned int*)g,
        (__attribute__((address_space(3))) unsigned int*)l, 16, 0, 0);
}

// ---------------- K1: fused prep: H = feat@W (MFMA) + teh table + packing ---
__global__ __launch_bounds__(256) void prep(
    const float* __restrict__ user_feat, const float* __restrict__ item_feat,
    const float* __restrict__ W_u, const float* __restrict__ W_i,
    const float* __restrict__ Wg_i, const float* __restrict__ Wg_u,
    const float* __restrict__ te_i, const float* __restrict__ te_u,
    const float* __restrict__ tk_i, const float* __restrict__ tk_u,
    unsigned int* __restrict__ H, float* __restrict__ tehT,
    unsigned short* __restrict__ WgPi, unsigned short* __restrict__ WgPu,
    unsigned short* __restrict__ tePi, unsigned short* __restrict__ tePu,
    unsigned short* __restrict__ tkPi, unsigned short* __restrict__ tkPu)
{
    const int tid = threadIdx.x;
    if (blockIdx.x < GEMM_BLKS) {
        const int lane = tid & 63, wid = tid >> 6;
        const int tile = blockIdx.x * 4 + wid;            // 16 rows per tile
        if (tile >= 3125) return;                         // 3125*16 = 50000 exact
        const int r0 = tile * 16;
        const float* src; const float* W; const float* teD;
        if (r0 < NUM_U) { src = user_feat + (size_t)r0 * D;           W = W_u; teD = te_u; }
        else            { src = item_feat + (size_t)(r0 - NUM_U) * D; W = W_i; teD = te_i; }
        const int q4 = lane >> 4, c16 = lane & 15;

        // B-frags: feat rows. B[n=c16][k=kt*32+q4*8+j], coalesced float4 pairs.
        short8x bf[2];
#pragma unroll
        for (int kt = 0; kt < 2; kt++) {
            const float* fp = src + c16 * D + kt * 32 + q4 * 8;
            float4 x = *(const float4*)fp;
            float4 y = *(const float4*)(fp + 4);
            union { short8x v; unsigned int u[4]; } t2;
            t2.u[0] = packbf(x.x, x.y); t2.u[1] = packbf(x.z, x.w);
            t2.u[2] = packbf(y.x, y.y); t2.u[3] = packbf(y.z, y.w);
            bf[kt] = t2.v;
        }
        // A-frags: W^T. A[m=c16+16mt][k] = W[k][c16+16mt]; W is 16KB, L1-hot.
        f32x4 zero4 = {0.f, 0.f, 0.f, 0.f};
        f32x4 acc[4];
#pragma unroll
        for (int mt = 0; mt < 4; mt++) acc[mt] = zero4;
#pragma unroll
        for (int kt = 0; kt < 2; kt++) {
#pragma unroll
            for (int mt = 0; mt < 4; mt++) {
                union { short8x v; unsigned short u[8]; } a;
#pragma unroll
                for (int j = 0; j < 8; j++)
                    a.u[j] = (unsigned short)f2bfbits(
                        W[(kt * 32 + q4 * 8 + j) * D + c16 + 16 * mt]);
                acc[mt] = __builtin_amdgcn_mfma_f32_16x16x32_bf16(a.v, bf[kt], acc[mt], 0, 0, 0);
            }
        }
        // D[m][n]: col(c16) = feat row n, reg row = m -> H col. uint2 stores.
        unsigned int* Hrow = H + (size_t)(r0 + c16) * 32;
#pragma unroll
        for (int mt = 0; mt < 4; mt++) {
            uint2 pk;
            pk.x = packbf(acc[mt][0], acc[mt][1]);
            pk.y = packbf(acc[mt][2], acc[mt][3]);
            *(uint2*)(Hrow + 8 * mt + 2 * q4) = pk;
        }

        // ---- teh pass: teh[node][r] = sum_d te[r][d] * H[node][d] ----
        // A = te (bf16, rows >= L zero), B = packed H rows just stored.
        // Same kt0->kt1 accumulation order as the in-attn version: bitwise id.
        if (tehT) {
            asm volatile("s_waitcnt vmcnt(0)" ::: "memory");   // own stores visible
            const char* Hb = (const char*)(H + (size_t)r0 * 32);
            short8x hb0 = *(const short8x*)(Hb + c16 * 128 + 0 * 64 + q4 * 16);
            short8x hb1 = *(const short8x*)(Hb + c16 * 128 + 1 * 64 + q4 * 16);
#pragma unroll
            for (int mt = 0; mt < 4; mt++) {
                f32x4 at = zero4;
                const int rowm = c16 + 16 * mt;
                union { short8x v; unsigned short u[8]; } a;
#pragma unroll
                for (int j = 0; j < 8; j++) {
                    int k = q4 * 8 + j;
                    a.u[j] = (rowm < L) ? (unsigned short)f2bfbits(teD[rowm * 64 + k])
                                        : (unsigned short)0;
                }
                at = __builtin_amdgcn_mfma_f32_16x16x32_bf16(a.v, hb0, at, 0, 0, 0);
#pragma unroll
                for (int j = 0; j < 8; j++) {
                    int k = 32 + q4 * 8 + j;
                    a.u[j] = (rowm < L) ? (unsigned short)f2bfbits(teD[rowm * 64 + k])
                                        : (unsigned short)0;
                }
                at = __builtin_amdgcn_mfma_f32_16x16x32_bf16(a.v, hb1, at, 0, 0, 0);
                // lane holds teh[r = 16mt+4q4+ri][node = r0+c16]: 4 consecutive r
                *(f32x4*)(tehT + (size_t)(r0 + c16) * 64 + 16 * mt + 4 * q4) = at;
            }
        }
    } else {
        int gid = (blockIdx.x - GEMM_BLKS) * 256 + tid;   // 16 blocks, gs=4096
        for (int idx = gid; idx < 8192; idx += 4096) {
            int n = idx >> 7, k = idx & 127;
            WgPi[idx] = (unsigned short)f2bfbits(Wg_i[k * 64 + n]);
            WgPu[idx] = (unsigned short)f2bfbits(Wg_u[k * 64 + n]);
        }
        {
            int idx = gid;                                // 4096 elements, 1 iter
            int r = idx >> 6, k = idx & 63;
            tePi[idx] = (r < L) ? (unsigned short)f2bfbits(te_i[r * 64 + k]) : 0;
            tePu[idx] = (r < L) ? (unsigned short)f2bfbits(te_u[r * 64 + k]) : 0;
            int d = idx >> 6, rr = idx & 63;
            tkPi[idx] = (rr < L) ? (unsigned short)f2bfbits(tk_i[rr * 64 + d]) : 0;
            tkPu[idx] = (rr < L) ? (unsigned short)f2bfbits(tk_u[rr * 64 + d]) : 0;
        }
    }
}

// ---------------- K2: fused attention, both sides, MFMA math ----------------
// Swizzle: LDS[row][pc] = G[row][pc ^ swz(row)], swz(row) = (row&7) ^
// (((row>>3)&3)<<1). Sums gather conflict-free; scores b128 <=2-way.
// dla (u16, dh|lm -> alpha|a1|beta) and escf (f32 e|e1|teh, cat u16 overlay
// ordered by data dependence + syncthreads -- r12-proven).
__global__ __launch_bounds__(256, 5) void attn_fused(
    const unsigned int* __restrict__ H,
    const float* __restrict__ user_feat, const float* __restrict__ item_feat,
    const unsigned short* __restrict__ WgPi, const unsigned short* __restrict__ WgPu,
    const unsigned short* __restrict__ tePi, const unsigned short* __restrict__ tePu,
    const unsigned short* __restrict__ tkPi, const unsigned short* __restrict__ tkPu,
    const int* __restrict__ item_nbr, const int* __restrict__ item_time,
    const int* __restrict__ user_nbr, const int* __restrict__ user_time,
    const float* __restrict__ tehT, float* __restrict__ out)
{
    __shared__ unsigned int lds[4 * PW3];   // 30208 B -> 5 blocks/CU

    const int tid = threadIdx.x, lane = tid & 63, wid = tid >> 6;
    const bool iside = blockIdx.x < (NUM_I / 4);
    const int bb = iside ? blockIdx.x : blockIdx.x - NUM_I / 4;
    const int n = bb * 4 + wid;
    const int src_base = iside ? 0 : NUM_U;
    const int dst_base = iside ? NUM_U : 0;
    const float* dst_feat = iside ? item_feat : user_feat;
    const unsigned short* WgP  = iside ? WgPi : WgPu;
    const unsigned short* teP  = iside ? tePi : tePu;
    const unsigned short* tekP = iside ? tkPi : tkPu;
    const int* nbr   = iside ? item_nbr  : user_nbr;
    const int* timev = iside ? item_time : user_time;
    float* outp = out + (iside ? (size_t)NUM_U * D : 0);

    const int q4 = lane >> 4, c16 = lane & 15;

    const unsigned int*   Hsrc = H + (size_t)src_base * 32;
    const unsigned short* Hs16 = (const unsigned short*)H + (size_t)src_base * 64;
    const unsigned short* Hd16 = (const unsigned short*)H + (size_t)dst_base * 64;

    // per-wave LDS slices
    unsigned int*   wld  = lds + wid * PW3;
    unsigned int*   mbw  = wld;                            // 50 rows x 32 dw, swizzled
    unsigned short* dla  = (unsigned short*)(wld + REG_OFF);   // u16 region
    float*          escf = (float*)(wld + REG_OFF + 96);       // f32 e|e1|teh
    unsigned short* cat  = (unsigned short*)(wld + REG_OFF + 96); // overlay [hl|hs]

    // ---- metadata ----
    int t   = (lane < L) ? timev[(size_t)n * L + lane] : 0;
    int nbv = (lane < L) ? nbr[(size_t)n * L + lane]  : 0;

    // ---- mailbox fill: rows 0..47 via global_load_lds (16B/lane, 8 rows/instr)
    {
        const int soff = (((lane & 7) ^ (lane >> 3)) << 4);   // g-invariant part
        const int rsel = (lane >> 3) << 2;                    // bpermute byte idx
#pragma unroll
        for (int g = 0; g < 6; g++) {
            int nb = __builtin_amdgcn_ds_bpermute(rsel + (g << 5), nbv);
            const char* gp = (const char*)(Hsrc + (size_t)(unsigned)nb * 32)
                             + (soff ^ ((g & 3) << 5));
            gload_lds16(gp, (char*)mbw + (g << 10));
        }
        // rows 48..49: one manual pass (2 rows x 32 dw over 64 lanes)
        int row = 48 + (lane >> 5), d = lane & 31;
        int nb = __builtin_amdgcn_ds_bpermute(row << 2, nbv);
        unsigned int v = Hsrc[(size_t)(unsigned)nb * 32 + d];
        int swzr = (row & 7) ^ (((row >> 3) & 3) << 1);
        mbw[(row << 5) + ((((d >> 2) ^ swzr) << 2) | (d & 3))] = v;
    }

    // ---- last (before rank so dh/lm loads issue early) ----
    unsigned int key2 = (lane < L) ? ((((unsigned)t) << 6) | (unsigned)(63 - lane)) : 0u;
    unsigned int m2 = key2;
#pragma unroll
    for (int s = 32; s; s >>= 1) { unsigned int o2 = __shfl_xor(m2, s); m2 = (o2 > m2) ? o2 : m2; }
    const int last = 63 - (int)(m2 & 63u);
    int nbl = __shfl(nbv, last);                      // last is wave-uniform
    unsigned short dh_u = Hd16[(size_t)n * 64 + lane];              // 2 u16 loads,
    unsigned short lm_u = Hs16[(size_t)(unsigned)nbl * 64 + lane];  // hide under rank

    // ---- rank ----
    unsigned int key = (lane < L) ? ((((unsigned)t) << 6) | (unsigned)lane) : 0u;
    int rank = 0;
#pragma unroll
    for (int j = 0; j < L; j++) {
        unsigned int kj = (unsigned int)rli((int)key, j);
        rank += (kj < key) ? 1 : 0;
    }
    int re_o = (lane < L) ? (L - 1 - rank) : lane;   // pad lanes: distinct slots

    // ---- th from precomputed table (load hidden under scores MFMAs) ----
    float th = 0.f;
    if (tehT) th = tehT[(size_t)(dst_base + n) * 64 + re_o];

    // ---- region phase 0: dh|lm (raw bf16, bit-identical) ----
    dla[lane]      = dh_u;
    dla[64 + lane] = lm_u;

    // ---- scores (+ teh fallback) via MFMA, kt-outer for ILP ----
    f32x4 zero4 = {0.f, 0.f, 0.f, 0.f};
    f32x4 acc_e[4];
#pragma unroll
    for (int nt = 0; nt < 4; nt++) acc_e[nt] = zero4;
    if (tehT) {
        __builtin_amdgcn_s_setprio(1);
#pragma unroll
        for (int kt = 0; kt < 2; kt++) {
            short8x afr = *(const short8x*)(dla + (c16 & 1) * 64 + kt * 32 + q4 * 8);
            int cc = kt * 4 + q4;
#pragma unroll
            for (int nt = 0; nt < 4; nt++) {
                int row = c16 + 16 * nt;
                int rowc = (row < MROWS) ? row : 0;    // rows >=50 masked later
                int swzr = (rowc & 7) ^ (((rowc >> 3) & 3) << 1);
                short8x bv = *(const short8x*)((const char*)mbw + rowc * 128
                                               + ((cc ^ swzr) << 4));
                acc_e[nt] = __builtin_amdgcn_mfma_f32_16x16x32_bf16(afr, bv, acc_e[nt], 0, 0, 0);
            }
        }
        __builtin_amdgcn_s_setprio(0);
    } else {
        f32x4 acc_t[4];
#pragma unroll
        for (int nt = 0; nt < 4; nt++) acc_t[nt] = zero4;
        __builtin_amdgcn_s_setprio(1);
#pragma unroll
        for (int kt = 0; kt < 2; kt++) {
            short8x afr = *(const short8x*)(dla + (c16 & 1) * 64 + kt * 32 + q4 * 8);
            int cc = kt * 4 + q4;
#pragma unroll
            for (int nt = 0; nt < 4; nt++) {
                int row = c16 + 16 * nt;
                int rowc = (row < MROWS) ? row : 0;
                int swzr = (rowc & 7) ^ (((rowc >> 3) & 3) << 1);
                short8x bv = *(const short8x*)((const char*)mbw + rowc * 128
                                               + ((cc ^ swzr) << 4));
                acc_e[nt] = __builtin_amdgcn_mfma_f32_16x16x32_bf16(afr, bv, acc_e[nt], 0, 0, 0);
                short8x bt = *(const short8x*)(teP + row * 64 + kt * 32 + q4 * 8);
                acc_t[nt] = __builtin_amdgcn_mfma_f32_16x16x32_bf16(afr, bt, acc_t[nt], 0, 0, 0);
            }
        }
        __builtin_amdgcn_s_setprio(0);
        if (q4 == 0) {
#pragma unroll
            for (int nt = 0; nt < 4; nt++) escf[128 + c16 + 16 * nt] = acc_t[nt][0];
        }
    }
    if (q4 == 0) {
#pragma unroll
        for (int nt = 0; nt < 4; nt++) {
            escf[c16 + 16 * nt]      = acc_e[nt][0];   // e
            escf[64 + c16 + 16 * nt] = acc_e[nt][1];   // e1
        }
    }
    float e  = escf[lane];
    float e1 = escf[64 + lane];
    if (!tehT) th = escf[128 + re_o];

    e = (e + th) * 0.125f;
    e1 *= 0.125f;
    if (lane >= L) { e = -3e38f; e1 = -3e38f; }

    // ---- dual softmax over neighbors ----
    float mx = e;
#pragma unroll
    for (int s = 32; s; s >>= 1) { float o2 = __shfl_xor(mx, s); mx = (o2 > mx) ? o2 : mx; }
    float ex = __expf(e - mx);
    float sm = ex;
#pragma unroll
    for (int s = 32; s; s >>= 1) sm += __shfl_xor(sm, s);
    float alpha = ex / sm;

    float mx1 = e1;
#pragma unroll
    for (int s = 32; s; s >>= 1) { float o2 = __shfl_xor(mx1, s); mx1 = (o2 > mx1) ? o2 : mx1; }
    float ex1 = __expf(e1 - mx1);
    float sm1 = ex1;
#pragma unroll
    for (int s = 32; s; s >>= 1) sm1 += __shfl_xor(sm1, s);
    float aw = ex1 / sm1;

    // ---- region phase 1: alpha|a1|beta (bf16, u16-only overlay on dla) ----
    // pad lanes: alpha == aw == 0 exactly -> rows >=50 contribute nothing below
    dla[lane]       = (unsigned short)f2bfbits(alpha);
    dla[64 + lane]  = (unsigned short)f2bfbits(aw);
    dla[128 + re_o] = (unsigned short)f2bfbits(alpha);   // beta[r]: alpha at rank r

    // ---- sums via MFMA: [alpha;a1]·M (conflict-free u16 gathers) + [beta]·tek^T
    f32x4 acc_s[4], acc_k[4];
#pragma unroll
    for (int nt = 0; nt < 4; nt++) { acc_s[nt] = zero4; acc_k[nt] = zero4; }
    __builtin_amdgcn_s_setprio(1);
#pragma unroll
    for (int kt = 0; kt < 2; kt++) {
        short8x aS = *(const short8x*)(dla + (c16 & 1) * 64 + kt * 32 + q4 * 8);
        short8x aB = *(const short8x*)(dla + 128 + kt * 32 + q4 * 8);
        int kr128[8];
#pragma unroll
        for (int i = 0; i < 8; i++) {
            int k = kt * 32 + q4 * 8 + i;
            if (kt) k = (k < MROWS) ? k : (k - 32);   // alpha=0 rows: any finite row
            kr128[i] = k << 7;                        // preserves k&7==i, (k>>3)&3==q4
        }
        const int qx = q4 << 1;                       // swizzle high bits
#pragma unroll
        for (int nt = 0; nt < 4; nt++) {
            int dc = c16 + 16 * nt;
            int tq = (dc >> 3) ^ qx;
            const char* cbase = (const char*)mbw + ((dc & 7) << 1);
            union { short8x v; unsigned short u[8]; } bu;
#pragma unroll
            for (int i = 0; i < 8; i++)
                bu.u[i] = *(const unsigned short*)(cbase + kr128[i] + ((tq ^ i) << 4));
            acc_s[nt] = __builtin_amdgcn_mfma_f32_16x16x32_bf16(aS, bu.v, acc_s[nt], 0, 0, 0);
            short8x bK = *(const short8x*)(tekP + dc * 64 + kt * 32 + q4 * 8);
            acc_k[nt] = __builtin_amdgcn_mfma_f32_16x16x32_bf16(aB, bK, acc_k[nt], 0, 0, 0);
        }
    }
    __builtin_amdgcn_s_setprio(0);
    // cat = [hl|hs] overlay onto escf (dead after softmax; ordered by dataflow)
    if (q4 == 0) {
#pragma unroll
        for (int nt = 0; nt < 4; nt++) {
            cat[c16 + 16 * nt]      = (unsigned short)f2bfbits(acc_s[nt][0] + acc_k[nt][0]);
            cat[64 + c16 + 16 * nt] = (unsigned short)f2bfbits(acc_s[nt][1]);
        }
    }
    __syncthreads();   // only barrier: epilogue mixes waves' cat rows

    // ---- epilogue: out = elu(cat @ Wg + f) ----
    short8x bfr[4];
#pragma unroll
    for (int tK = 0; tK < 4; tK++)
        bfr[tK] = *(const short8x*)(WgP + (wid * 16 + c16) * 128 + tK * 32 + q4 * 8);

    const unsigned short* catw =
        (const unsigned short*)(lds + (lane & 3) * PW3 + REG_OFF + 96);
    f32x4 acc = zero4;
#pragma unroll
    for (int tK = 0; tK < 4; tK++) {
        short8x a = *(const short8x*)(catw + tK * 32 + q4 * 8);
        acc = __builtin_amdgcn_mfma_f32_16x16x32_bf16(a, bfr[tK], acc, 0, 0, 0);
    }
    float r01 = (q4 & 1) ? acc[1] : acc[0];
    float r23 = (q4 & 1) ? acc[3] : acc[2];
    float pv  = (q4 & 2) ? r23 : r01;

    int node = bb * 4 + q4;
    float fres = dst_feat[(size_t)node * D + wid * 16 + c16];
    float oo = pv + fres;
    oo = (oo > 0.f) ? oo : (__expf(oo) - 1.f);
    outp[(size_t)node * D + wid * 16 + c16] = oo;
}

// ---------------- fallback: round-5 monolith (passed, 447us) ---------------
__global__ __launch_bounds__(256) void attn_mono(
    const float* __restrict__ src_feat, const float* __restrict__ dst_feat,
    const float* __restrict__ W_src, const float* __restrict__ W_dst,
    const float* __restrict__ Wg, const float* __restrict__ te,
    const float* __restrict__ tek, const int* __restrict__ nbr,
    const int* __restrict__ timev, float* __restrict__ out)
{
    __shared__ unsigned int ws32[64 * 33];
    __shared__ unsigned int te32[L * 33];
    __shared__ unsigned int mbs[4][L * 33];
    const int tid = threadIdx.x, lane = tid & 63, wid = tid >> 6;
    const int n = blockIdx.x * 4 + wid;
    {
        const float2* Wf2 = (const float2*)W_src;
        const float2* Te2 = (const float2*)te;
        for (int idx = tid; idx < 2048; idx += 256) {
            float2 w = Wf2[idx];
            ws32[(idx >> 5) * 33 + (idx & 31)] = packbf(w.x, w.y);
            if (idx < 1600) {
                float2 t2 = Te2[idx];
                te32[(idx >> 5) * 33 + (idx & 31)] = packbf(t2.x, t2.y);
            }
        }
    }
    __syncthreads();
    int t  = (lane < L) ? timev[(size_t)n * L + lane] : 0;
    int nb = (lane < L) ? nbr[(size_t)n * L + lane]  : 0;
    unsigned int key  = (lane < L) ? ((((unsigned)t) << 6) | (unsigned)lane) : 0u;
    unsigned int key2 = (lane < L) ? ((((unsigned)t) << 6) | (unsigned)(63 - lane)) : 0u;
    int rank = 0;
#pragma unroll
    for (int j = 0; j < L; j++) {
        unsigned int kj = (unsigned int)rli((int)key, j);
        rank += (kj < key) ? 1 : 0;
    }
    int re_o = (lane < L) ? (L - 1 - rank) : 0;
    unsigned int m2 = key2;
#pragma unroll
    for (int s = 32; s; s >>= 1) { unsigned int o2 = __shfl_xor(m2, s); m2 = (o2 > m2) ? o2 : m2; }
    const int last = 63 - (int)(m2 & 63u);
    const int rr = (lane < L) ? lane : (L - 1);
    float f = dst_feat[(size_t)n * D + lane];
    float dh;
    {
        float b0 = 0.f, b1 = 0.f, b2 = 0.f, b3 = 0.f;
#pragma unroll
        for (int k = 0; k < 64; k += 4) {
            b0 += rl(f, k + 0) * W_dst[(k + 0) * 64 + lane];
            b1 += rl(f, k + 1) * W_dst[(k + 1) * 64 + lane];
            b2 += rl(f, k + 2) * W_dst[(k + 2) * 64 + lane];
            b3 += rl(f, k + 3) * W_dst[(k + 3) * 64 + lane];
        }
        dh = (b0 + b1) + (b2 + b3);
    }
    float v1;
    {
        float b0 = 0.f, b1 = 0.f, b2 = 0.f, b3 = 0.f;
#pragma unroll
        for (int j = 0; j < 32; j += 2) {
            unsigned int u0 = ws32[lane * 33 + j];
            unsigned int u1 = ws32[lane * 33 + j + 1];
            b0 += lof(u0) * rl(dh, 2 * j + 0);
            b1 += hif(u0) * rl(dh, 2 * j + 1);
            b2 += lof(u1) * rl(dh, 2 * j + 2);
            b3 += hif(u1) * rl(dh, 2 * j + 3);
        }
        v1 = (b0 + b1) + (b2 + b3);
    }
    unsigned int* mbw = mbs[wid];
    {
        const float2* src2 = (const float2*)src_feat;
        int half = lane >> 5, col = lane & 31;
#pragma unroll
        for (int l = 0; l < L; l += 2) {
            int ra = rli(nb, l), rb = rli(nb, l + 1);
            int r = half ? rb : ra;
            float2 v = src2[(size_t)r * 32 + col];
            mbw[(l + half) * 33 + col] = packbf(v.x, v.y);
        }
    }
    __syncthreads();
    unsigned int ul = mbw[last * 33 + (lane >> 1)];
    float rlast = (lane & 1) ? hif(ul) : lof(ul);
    float g;
    {
        float b0 = 0.f, b1 = 0.f, b2 = 0.f, b3 = 0.f;
#pragma unroll
        for (int k = 0; k < 64; k += 4) {
            b0 += rl(rlast, k + 0) * W_src[(k + 0) * 64 + lane];
            b1 += rl(rlast, k + 1) * W_src[(k + 1) * 64 + lane];
            b2 += rl(rlast, k + 2) * W_src[(k + 2) * 64 + lane];
            b3 += rl(rlast, k + 3) * W_src[(k + 3) * 64 + lane];
        }
        g = (b0 + b1) + (b2 + b3);
    }
    float v2;
    {
        float b0 = 0.f, b1 = 0.f, b2 = 0.f, b3 = 0.f;
#pragma unroll
        for (int j = 0; j < 32; j += 2) {
            unsigned int u0 = ws32[lane * 33 + j];
            unsigned int u1 = ws32[lane * 33 + j + 1];
            b0 += lof(u0) * rl(g, 2 * j + 0);
            b1 += hif(u0) * rl(g, 2 * j + 1);
            b2 += lof(u1) * rl(g, 2 * j + 2);
            b3 += hif(u1) * rl(g, 2 * j + 3);
        }
        v2 = (b0 + b1) + (b2 + b3);
    }
    float teh;
    {
        float b0 = 0.f, b1 = 0.f, b2 = 0.f, b3 = 0.f;
#pragma unroll
        for (int j = 0; j < 32; j += 2) {
            unsigned int u0 = te32[rr * 33 + j];
            unsigned int u1 = te32[rr * 33 + j + 1];
            b0 += lof(u0) * rl(dh, 2 * j + 0);
            b1 += hif(u0) * rl(dh, 2 * j + 1);
            b2 += lof(u1) * rl(dh, 2 * j + 2);
            b3 += hif(u1) * rl(dh, 2 * j + 3);
        }
        teh = (b0 + b1) + (b2 + b3);
    }
    float e, e1;
    {
        float ea = 0.f, eb = 0.f, qa = 0.f, qb = 0.f;
#pragma unroll
        for (int j = 0; j < 32; j += 2) {
            unsigned int u0 = mbw[rr * 33 + j];
            unsigned int u1 = mbw[rr * 33 + j + 1];
            float m0 = lof(u0), m1 = hif(u0), m2f = lof(u1), m3 = hif(u1);
            ea += m0 * rl(v1, 2 * j + 0) + m1 * rl(v1, 2 * j + 1);
            eb += m2f * rl(v1, 2 * j + 2) + m3 * rl(v1, 2 * j + 3);
            qa += m0 * rl(v2, 2 * j + 0) + m1 * rl(v2, 2 * j + 1);
            qb += m2f * rl(v2, 2 * j + 2) + m3 * rl(v2, 2 * j + 3);
        }
        e = ea + eb; e1 = qa + qb;
    }
    e = (e + __shfl(teh, re_o)) * 0.125f;
    e1 *= 0.125f;
    if (lane >= L) { e = -3e38f; e1 = -3e38f; }
    float mx = e;
#pragma unroll
    for (int s = 32; s; s >>= 1) { float o2 = __shfl_xor(mx, s); mx = (o2 > mx) ? o2 : mx; }
    float ex = __expf(e - mx);
    float sm = ex;
#pragma unroll
    for (int s = 32; s; s >>= 1) sm += __shfl_xor(sm, s);
    float alpha = ex / sm;
    float mx1 = e1;
#pragma unroll
    for (int s = 32; s; s >>= 1) { float o2 = __shfl_xor(mx1, s); mx1 = (o2 > mx1) ? o2 : mx1; }
    float ex1 = __expf(e1 - mx1);
    float sm1 = ex1;
#pragma unroll
    for (int s = 32; s; s >>= 1) sm1 += __shfl_xor(sm1, s);
    float aw = ex1 / sm1;
    float sl, ss, tacc;
    {
        float sA = 0.f, sB = 0.f, hA = 0.f, hB = 0.f, tA = 0.f, tB = 0.f;
        int hcol = lane >> 1, odd = lane & 1;
#pragma unroll
        for (int l = 0; l < L; l += 2) {
            float saA = rl(alpha, l),     s1A = rl(aw, l);
            float saB = rl(alpha, l + 1), s1B = rl(aw, l + 1);
            int   roA = rli(re_o, l),     roB = rli(re_o, l + 1);
            unsigned int uA = mbw[(l + 0) * 33 + hcol];
            unsigned int uB = mbw[(l + 1) * 33 + hcol];
            float mA = odd ? hif(uA) : lof(uA);
            float mB = odd ? hif(uB) : lof(uB);
            sA += saA * mA; hA += s1A * mA; tA += saA * tek[roA * 64 + lane];
            sB += saB * mB; hB += s1B * mB; tB += saB * tek[roB * 64 + lane];
        }
        sl = sA + sB; ss = hA + hB; tacc = tA + tB;
    }
    float hl, hs;
    {
        float lA = 0.f, lB = 0.f, sA = 0.f, sB = 0.f;
#pragma unroll
        for (int k = 0; k < 64; k += 2) {
            float w0 = W_src[(k + 0) * 64 + lane];
            float w1 = W_src[(k + 1) * 64 + lane];
            lA += rl(sl, k + 0) * w0; sA += rl(ss, k + 0) * w0;
            lB += rl(sl, k + 1) * w1; sB += rl(ss, k + 1) * w1;
        }
        hl = tacc + lA + lB; hs = sA + sB;
    }
    float o;
    {
        float o0 = 0.f, o1 = 0.f, o2 = 0.f, o3 = 0.f;
#pragma unroll
        for (int k = 0; k < 64; k += 2) {
            o0 += rl(hl, k + 0) * Wg[(k + 0) * 64 + lane];
            o1 += rl(hl, k + 1) * Wg[(k + 1) * 64 + lane];
            o2 += rl(hs, k + 0) * Wg[(k + 64) * 64 + lane];
            o3 += rl(hs, k + 1) * Wg[(k + 65) * 64 + lane];
        }
        o = f + (o0 + o1) + (o2 + o3);
    }
    o = (o > 0.f) ? o : (__expf(o) - 1.f);
    out[(size_t)n * D + lane] = o;
}

extern "C" void kernel_launch(void* const* d_in, const int* in_sizes, int n_in,
                              void* d_out, int out_size, void* d_ws, size_t ws_size,
                              hipStream_t stream) {
    const float* user_feat = (const float*)d_in[0];
    const float* item_feat = (const float*)d_in[1];
    const float* W_u  = (const float*)d_in[2];
    const float* W_i  = (const float*)d_in[3];
    const float* Wg_u = (const float*)d_in[4];
    const float* Wg_i = (const float*)d_in[5];
    const float* i_te   = (const float*)d_in[6];
    const float* i_te_k = (const float*)d_in[7];
    const float* u_te   = (const float*)d_in[8];
    const float* u_te_k = (const float*)d_in[9];
    const int* item_nbr  = (const int*)d_in[10];
    const int* item_time = (const int*)d_in[11];
    const int* user_nbr  = (const int*)d_in[12];
    const int* user_time = (const int*)d_in[13];
    (void)in_sizes; (void)n_in; (void)out_size;

    float* outp = (float*)d_out;
    const size_t H_BYTES   = (size_t)(NUM_U + NUM_I) * 32 * 4;          // 6.4 MB
    const size_t AUX_BYTES = 2 * 16384 + 4 * 8192;                      // 64 KB
    const size_t TEH_BYTES = (size_t)(NUM_U + NUM_I) * 64 * 4;          // 12.8 MB
    const size_t NEED  = H_BYTES + AUX_BYTES;
    const size_t NEED2 = NEED + TEH_BYTES;

    if (ws_size >= NEED) {
        unsigned int* Hp = (unsigned int*)d_ws;
        unsigned char* aux = (unsigned char*)d_ws + H_BYTES;
        unsigned short* WgPi = (unsigned short*)(aux);
        unsigned short* WgPu = (unsigned short*)(aux + 16384);
        unsigned short* tePi = (unsigned short*)(aux + 32768);
        unsigned short* tePu = (unsigned short*)(aux + 40960);
        unsigned short* tkPi = (unsigned short*)(aux + 49152);
        unsigned short* tkPu = (unsigned short*)(aux + 57344);
        float* tehp = (ws_size >= NEED2)
                      ? (float*)((unsigned char*)d_ws + H_BYTES + AUX_BYTES)
                      : (float*)nullptr;

        prep<<<GEMM_BLKS + 16, 256, 0, stream>>>(user_feat, item_feat, W_u, W_i,
                                       Wg_i, Wg_u, i_te, u_te, i_te_k, u_te_k,
                                       Hp, tehp, WgPi, WgPu, tePi, tePu, tkPi, tkPu);
        attn_fused<<<(NUM_I + NUM_U) / 4, 256, 0, stream>>>(
            Hp, user_feat, item_feat, WgPi, WgPu, tePi, tePu, tkPi, tkPu,
            item_nbr, item_time, user_nbr, user_time, tehp, outp);
    } else {
        attn_mono<<<NUM_I / 4, 256, 0, stream>>>(
            user_feat, item_feat, W_u, W_i, Wg_i, i_te, i_te_k,
            item_nbr, item_time, outp + (size_t)NUM_U * D);
        attn_mono<<<NUM_U / 4, 256, 0, stream>>>(
            item_feat, user_feat, W_i, W_u, Wg_u, u_te, u_te_k,
            user_nbr, user_time, outp);
    }
}